// Round 8
// baseline (490.898 us; speedup 1.0000x reference)
//
#include <hip/hip_runtime.h>
#include <math.h>

#define B_ 16
#define S_ 1024
#define D_ 1024
#define NH_ 16
#define M_TOT (B_ * S_)

typedef __attribute__((ext_vector_type(8))) short short8v;
typedef __attribute__((ext_vector_type(4))) short short4v;
typedef __attribute__((ext_vector_type(4))) float float4v;
typedef __attribute__((ext_vector_type(4))) unsigned int uint4v;

static __device__ __forceinline__ unsigned short f2bf(float f) {
  union { float f; unsigned u; } x; x.f = f;
  unsigned r = (x.u + 0x7fffu + ((x.u >> 16) & 1u)) >> 16;
  return (unsigned short)r;
}
static __device__ __forceinline__ float bf2f(unsigned short u) {
  union { unsigned u; float f; } x; x.u = ((unsigned)u) << 16;
  return x.f;
}

// pack two f32 -> bf16x2 word, RNE (a -> low half).  Manual f2bf (known-RNE);
// v_cvt_pk_bf16_f32 failed accuracy in round 1 (rounding-mode mismatch).
static __device__ __forceinline__ unsigned pack2bf(float a, float b) {
  return ((unsigned)f2bf(b) << 16) | (unsigned)f2bf(a);
}

// async global->LDS, 16B per lane; LDS dest = wave-uniform base + lane*16 (m104)
static __device__ __forceinline__ void load_lds16(const unsigned short* g, unsigned short* l) {
  __builtin_amdgcn_global_load_lds(
      (const __attribute__((address_space(1))) unsigned int*)g,
      (__attribute__((address_space(3))) unsigned int*)l, 16, 0, 0);
}

// ---------------------------------------------------------------- fused prep
// [0, 16384)        : x f32 -> bf16 (4 elems/thread)
// [16384, 20480)    : 4 weight matrices f32 -> bf16 (4 elems/thread)
// [20480, 20514)    : RoPE tables
__global__ __launch_bounds__(256) void prep(
    const float* __restrict__ x, unsigned short* __restrict__ xb,
    const float* __restrict__ w0, const float* __restrict__ w1,
    const float* __restrict__ w2, const float* __restrict__ w3,
    unsigned short* __restrict__ wdst,
    float* __restrict__ cos1, float* __restrict__ sin1,
    float* __restrict__ cos2, float* __restrict__ sin2) {
  const int bid = blockIdx.x;
  if (bid < 16384) {
    int i = bid * 256 + threadIdx.x;       // < M_TOT*D_/4
    float4 v = ((const float4*)x)[i];
    unsigned short tt[4] = {f2bf(v.x), f2bf(v.y), f2bf(v.z), f2bf(v.w)};
    ((short4v*)xb)[i] = *(short4v*)tt;
  } else if (bid < 20480) {
    int wi = (bid - 16384) * 256 + threadIdx.x;   // < 4*D_*D_/4
    int m = wi >> 18;                             // matrix (block-uniform)
    int i = wi & 262143;
    const float* src = (m == 0) ? w0 : (m == 1) ? w1 : (m == 2) ? w2 : w3;
    float4 v = ((const float4*)src)[i];
    unsigned short tt[4] = {f2bf(v.x), f2bf(v.y), f2bf(v.z), f2bf(v.w)};
    ((short4v*)(wdst + (size_t)m * D_ * D_))[i] = *(short4v*)tt;
  } else {
    int t = (bid - 20480) * 256 + threadIdx.x;
    if (t < S_ * 8) {
      int s = t >> 3, i = t & 7;
      double ang = (double)s * pow(10000.0, -(double)i / 8.0);
      cos1[t] = (float)cos(ang);
      sin1[t] = (float)sin(ang);
    } else if (t < S_ * 8 + 384) {
      int u = t - S_ * 8;
      int p = u / 12, j = u - p * 12;
      double ang = (double)p * pow(10000.0, -(double)j / 12.0);
      cos2[u] = (float)cos(ang);
      sin2[u] = (float)sin(ang);
    }
  }
}

// ---------------------------------------------------------------- bf16 MFMA GEMM
// C[M,1024] = A[M,1024] @ W[1024,1024]^T + bias.  128x128 tile, BK=32.
// Round-7: 3-buffer counted-vmcnt pipeline (T4) -> 731 TF.  Round-8 adds the
// T2 XOR swizzle: rows are 64B, so linear reads put a group's 16 lanes on 2
// bank-quads (8-way conflict, 12.6M cycles/dispatch).  Swizzle (rule #21,
// both-sides): LDS slot (row,chunk16B) holds global (row, chunk^((row>>1)&3)).
//   stage: source col = ((L&3) ^ ((L>>3)&3))*8   (dest stays linear for DMA)
//   read : chunk = g ^ ((c>>1)&3)                (per-lane constant)
// After: banks = 16(c&1)+4(g^((c>>1)&3)) -> 8 distinct quads covering all 32
// banks, 2 lanes/quad = free (m136).  Involution, bijective per row.
// grid.y selects {W, bias, C} (QKV fused in one launch; O uses y=0).
template <bool BF16OUT>
__global__ __launch_bounds__(256) void gemm_mfma(
    const unsigned short* __restrict__ A, const unsigned short* __restrict__ Wall,
    const float* __restrict__ b0, const float* __restrict__ b1,
    const float* __restrict__ b2, void* __restrict__ Cout) {
  __shared__ unsigned short As[3][128 * 32];
  __shared__ unsigned short Bs[3][128 * 32];
  const int y = blockIdx.y;
  const unsigned short* W = Wall + (size_t)y * D_ * D_;
  const float* bias = (y == 0) ? b0 : (y == 1) ? b1 : b2;
  const int t = threadIdx.x;
  const int w = t >> 6, L = t & 63;
  const int c = L & 15, g = L >> 4;
  const int id = blockIdx.x;
  const int xcd = id & 7, slot = id >> 3;
  const int bn = (slot & 7) * 128;
  const int bm = ((slot >> 3) * 8 + xcd) * 128;

  const int srow = w * 32 + (L >> 2);
  const int sko = ((L & 3) ^ ((L >> 3) & 3)) * 8;   // T2 pre-swizzled source col
  const unsigned short* gA = A + (size_t)(bm + srow) * D_ + sko;
  const unsigned short* gB = W + (size_t)(bn + srow) * D_ + sko;

  const int wm = (w >> 1) * 64, wn = (w & 1) * 64;
  const int rg = 8 * (g ^ ((c >> 1) & 3));          // T2 swizzled read chunk

  float4v acc[4][4];
#pragma unroll
  for (int i = 0; i < 4; ++i)
#pragma unroll
    for (int j = 0; j < 4; ++j) acc[i][j] = (float4v){0.f, 0.f, 0.f, 0.f};

#define GS(buf, kt_)                                                   \
  {                                                                    \
    load_lds16(gA + (kt_) * 32, &As[buf][w * 1024]);                   \
    load_lds16(gA + (kt_) * 32 + 16 * D_, &As[buf][w * 1024 + 512]);   \
    load_lds16(gB + (kt_) * 32, &Bs[buf][w * 1024]);                   \
    load_lds16(gB + (kt_) * 32 + 16 * D_, &Bs[buf][w * 1024 + 512]);   \
  }
#define VWAIT4 asm volatile("s_waitcnt vmcnt(4)" ::: "memory")
#define VWAIT0 asm volatile("s_waitcnt vmcnt(0)" ::: "memory")
#define BARRIER asm volatile("s_barrier" ::: "memory")
#define COMPUTE(cur)                                                     \
  {                                                                      \
    short8v af[4], bf[4];                                                \
    _Pragma("unroll")                                                    \
    for (int i = 0; i < 4; ++i)                                          \
      af[i] = *(const short8v*)&As[cur][(wm + 16 * i + c) * 32 + rg];    \
    _Pragma("unroll")                                                    \
    for (int j = 0; j < 4; ++j)                                          \
      bf[j] = *(const short8v*)&Bs[cur][(wn + 16 * j + c) * 32 + rg];    \
    _Pragma("unroll")                                                    \
    for (int i = 0; i < 4; ++i)                                          \
      _Pragma("unroll")                                                  \
      for (int j = 0; j < 4; ++j)                                        \
        acc[i][j] = __builtin_amdgcn_mfma_f32_16x16x32_bf16(             \
            af[i], bf[j], acc[i][j], 0, 0, 0);                           \
  }

  GS(0, 0);          // outstanding 4
  GS(1, 1);          // outstanding 8
#pragma unroll 1
  for (int s = 0; s < 30; s += 3) {
    VWAIT4; BARRIER; GS(2, s + 2); COMPUTE(0);   // step s
    VWAIT4; BARRIER; GS(0, s + 3); COMPUTE(1);   // step s+1
    VWAIT4; BARRIER; GS(1, s + 4); COMPUTE(2);   // step s+2
  }
  VWAIT4; BARRIER; COMPUTE(0);                   // step 30 (k30 in buf0)
  VWAIT0; BARRIER; COMPUTE(1);                   // step 31 (k31 in buf1)
#undef GS
#undef VWAIT4
#undef VWAIT0
#undef BARRIER
#undef COMPUTE
  unsigned short* Cb = (unsigned short*)Cout + (size_t)y * M_TOT * D_;
#pragma unroll
  for (int i = 0; i < 4; ++i)
#pragma unroll
    for (int r = 0; r < 4; ++r) {
      const size_t row = (size_t)bm + wm + 16 * i + 4 * g + r;
#pragma unroll
      for (int j = 0; j < 4; ++j) {
        const int col = bn + wn + 16 * j + c;
        float vv = acc[i][j][r] + bias[col];
        if (BF16OUT)
          Cb[row * D_ + col] = f2bf(vv);
        else
          ((float*)Cout)[row * D_ + col] = vv;
      }
    }
}

// ---------------------------------------------------------------- fused postproc
// [0, 32768)      : RoPE on Q (scale 0.125 -- EXACT in bf16; log2e-fold is
//                   permanently banned: 0.125*log2e is not bf16-representable
//                   and re-quantizes Q (round-5 failure, absmax 3.4e-3))
// [32768, 65536)  : RoPE on K (scale 1.0)
// [65536, 69632)  : V transpose vb [b][s][hd*64+n] -> vT [b][hd][n][s]
__global__ __launch_bounds__(256) void postproc(
    unsigned short* __restrict__ qb, unsigned short* __restrict__ kbuf,
    const unsigned short* __restrict__ vb, unsigned short* __restrict__ vT,
    const float* __restrict__ cos1, const float* __restrict__ sin1,
    const float* __restrict__ cos2, const float* __restrict__ sin2) {
  __shared__ unsigned short T[64][72];
  const int bid = blockIdx.x;
  if (bid < 65536) {
    unsigned short* q = (bid < 32768) ? qb : kbuf;
    const float scale = (bid < 32768) ? 0.125f : 1.0f;
    int tid = (bid & 32767) * 256 + threadIdx.x;
    int u = tid & 511;
    int m = tid >> 9;
    int s = m & (S_ - 1);
    int head = u >> 5, w = u & 31;
    size_t base = (size_t)m * D_ + head * 64;
    size_t c0, c1;
    float cv, sv;
    if (w < 8) {
      c0 = base + 2 * w; c1 = c0 + 1;
      cv = cos1[s * 8 + w]; sv = sin1[s * 8 + w];
    } else if (w < 20) {
      int j = w - 8, x = s & 31;
      c0 = base + 16 + j; c1 = base + 28 + j;
      cv = cos2[x * 12 + j]; sv = sin2[x * 12 + j];
    } else {
      int j = w - 20, yy = s >> 5;
      c0 = base + 40 + j; c1 = base + 52 + j;
      cv = cos2[yy * 12 + j]; sv = sin2[yy * 12 + j];
    }
    float a = bf2f(q[c0]), b = bf2f(q[c1]);
    q[c0] = f2bf((a * cv - b * sv) * scale);
    q[c1] = f2bf((a * sv + b * cv) * scale);
  } else {
    const int tb = bid - 65536;            // < 4096 = 16 st * 16 hd * 16 b
    const int t = threadIdx.x;
    const int st0 = (tb & 15) * 64;
    const int hd = (tb >> 4) & 15, b = tb >> 8;
    const unsigned short* src = vb + ((size_t)b * S_ + st0) * D_ + hd * 64;
#pragma unroll
    for (int rep = 0; rep < 4; ++rep) {
      int id = t + rep * 256;
      int s = id >> 4, n4 = (id & 15) * 4;
      short4v val = *(const short4v*)(src + (size_t)s * D_ + n4);
      T[n4 + 0][s] = val[0]; T[n4 + 1][s] = val[1];
      T[n4 + 2][s] = val[2]; T[n4 + 3][s] = val[3];
    }
    __syncthreads();
    unsigned short* dst = vT + ((size_t)(b * NH_ + hd) * 64) * S_ + st0;
#pragma unroll
    for (int rep = 0; rep < 2; ++rep) {
      int id = t + rep * 256;
      int n = id >> 3, s8 = (id & 7) * 8;
      unsigned short tmp[8];
#pragma unroll
      for (int u2 = 0; u2 < 8; ++u2) tmp[u2] = T[n][s8 + u2];
      *(short8v*)(dst + (size_t)n * S_ + s8) = *(short8v*)tmp;
    }
  }
}

// ---------------------------------------------------------------- MFMA flash attention
// grid = 2048 linear, swizzled: xcd=id%8, slot=id/8, qt=slot%8,
// pair=(slot/8)*8+xcd.  8 qt-blocks of a pair sit on ONE XCD -> K/V L2-resident.
// Block-shared double-buffered LDS K/V staging (round-4 2x win), swapped QK^T
// with in-register softmax, bpermute P-redistribution.  Unchanged from the
// passing round-4/6/7 kernel.
__global__ __launch_bounds__(256, 4) void attn_mfma(
    const unsigned short* __restrict__ qb, const unsigned short* __restrict__ kb,
    const unsigned short* __restrict__ vT, unsigned short* __restrict__ out) {
  __shared__ unsigned short KV[2][2][4096];   // [dbuf][K/V][64 rows x 64 elems]
  const int t = threadIdx.x;
  const int w = t >> 6;
  const int L = t & 63;
  const int c = L & 15;
  const int g = L >> 4;
  const int id = blockIdx.x;
  const int xcd = id & 7, slot = id >> 3;
  const int qt = slot & 7;
  const int pair = (slot >> 3) * 8 + xcd;
  const int b = pair >> 4, hd = pair & 15;
  const size_t mrow0 = (size_t)b * S_ + qt * 128 + w * 32;
  const int dcol0 = hd * 64;

  // staging lane geometry: lane L writes LDS bytes [seg*1024 + L*16, +16);
  // holds tile row seg*8+(L>>3), col-chunk (L&7); inverse-swizzle the SOURCE
  // col-chunk so reads can XOR with ((row&7)<<4)  (rule #21).
  const int lrow = L >> 3;
  const int lcol = ((L & 7) ^ lrow) * 8;

  // bpermute pull addresses (byte = 4*src_lane)
  const int a_lo = (((L & 16) ? 32 : 0) + c) * 4;
  const int a_hi = a_lo + 64;
  const bool ghi = (L >= 32);
  const int swz = (c & 7) << 3;                   // read-side XOR (elems)

  short8v aq[2][2];
#pragma unroll
  for (int i = 0; i < 2; ++i)
#pragma unroll
    for (int st = 0; st < 2; ++st)
      aq[i][st] = *(const short8v*)(qb + (mrow0 + 16 * i + c) * D_ + dcol0 + 32 * st + 8 * g);

  float4v oacc[2][4];
  float lsum[2] = {0.f, 0.f};
#pragma unroll
  for (int i = 0; i < 2; ++i)
#pragma unroll
    for (int jv = 0; jv < 4; ++jv) oacc[i][jv] = (float4v){0.f, 0.f, 0.f, 0.f};

  const unsigned short* vbase = vT + (size_t)(b * NH_ + hd) * 64 * S_;
  const unsigned short* kbb = kb + (size_t)b * S_ * D_ + dcol0;

#define STAGE(buf, kt_)                                                          \
  {                                                                              \
    _Pragma("unroll")                                                            \
    for (int e = 0; e < 2; ++e) {                                                \
      const int seg = 2 * w + e;                                                 \
      const int row = seg * 8 + lrow;                                            \
      load_lds16(kbb + (size_t)((kt_) * 64 + row) * D_ + lcol,                   \
                 &KV[buf][0][seg * 512]);                                        \
      load_lds16(vbase + (size_t)row * S_ + (kt_) * 64 + lcol,                   \
                 &KV[buf][1][seg * 512]);                                        \
    }                                                                            \
  }

  STAGE(0, 0);
  asm volatile("s_waitcnt vmcnt(0)" ::: "memory");
  __syncthreads();

#pragma unroll 1
  for (int kt = 0; kt < 16; ++kt) {
    const int cur = kt & 1;
    if (kt < 15) STAGE(cur ^ 1, kt + 1);
#pragma unroll
    for (int st = 0; st < 2; ++st) {
      short8v vfh[4];
#pragma unroll
      for (int jv = 0; jv < 4; ++jv)
        vfh[jv] = *(const short8v*)&KV[cur][1][((16 * jv + c) * 64 + st * 32 + 8 * g) ^ swz];
      short8v kfh[2][2];
#pragma unroll
      for (int jl = 0; jl < 2; ++jl)
#pragma unroll
        for (int h = 0; h < 2; ++h)
          kfh[jl][h] = *(const short8v*)&KV[cur][0][((16 * (2 * st + jl) + c) * 64 + h * 32 + 8 * g) ^ swz];
      float4v sacch[2][2];
#pragma unroll
      for (int i = 0; i < 2; ++i)
#pragma unroll
        for (int jl = 0; jl < 2; ++jl) sacch[i][jl] = (float4v){0.f, 0.f, 0.f, 0.f};
      __builtin_amdgcn_s_setprio(1);
#pragma unroll
      for (int jl = 0; jl < 2; ++jl)
#pragma unroll
        for (int i = 0; i < 2; ++i) {
          sacch[i][jl] = __builtin_amdgcn_mfma_f32_16x16x32_bf16(kfh[jl][0], aq[i][0], sacch[i][jl], 0, 0, 0);
          sacch[i][jl] = __builtin_amdgcn_mfma_f32_16x16x32_bf16(kfh[jl][1], aq[i][1], sacch[i][jl], 0, 0, 0);
        }
      __builtin_amdgcn_s_setprio(0);
      // in-register softmax: exp + lane-local row-sum + pack pairs to bf16 (RNE)
      unsigned pkh[2][2][2];
#pragma unroll
      for (int i = 0; i < 2; ++i)
#pragma unroll
        for (int jl = 0; jl < 2; ++jl) {
          float p0 = __expf(sacch[i][jl][0]);
          float p1 = __expf(sacch[i][jl][1]);
          float p2 = __expf(sacch[i][jl][2]);
          float p3 = __expf(sacch[i][jl][3]);
          lsum[i] += (p0 + p1) + (p2 + p3);
          pkh[i][jl][0] = pack2bf(p0, p1);
          pkh[i][jl][1] = pack2bf(p2, p3);
        }
      short8v aph[2];
#pragma unroll
      for (int i = 0; i < 2; ++i) {
        uint4v wv;
#pragma unroll
        for (int q2 = 0; q2 < 4; ++q2) {
          const int addr = (q2 & 2) ? a_hi : a_lo;
          int vlo = __builtin_amdgcn_ds_bpermute(addr, (int)pkh[i][0][q2 & 1]);
          int vhi = __builtin_amdgcn_ds_bpermute(addr, (int)pkh[i][1][q2 & 1]);
          wv[q2] = (unsigned)(ghi ? vhi : vlo);
        }
        aph[i] = *(short8v*)&wv;
      }
      __builtin_amdgcn_s_setprio(1);
#pragma unroll
      for (int jv = 0; jv < 4; ++jv)
#pragma unroll
        for (int i = 0; i < 2; ++i)
          oacc[i][jv] = __builtin_amdgcn_mfma_f32_16x16x32_bf16(aph[i], vfh[jv], oacc[i][jv], 0, 0, 0);
      __builtin_amdgcn_s_setprio(0);
    }
    asm volatile("s_waitcnt vmcnt(0)" ::: "memory");
    __syncthreads();
  }
#undef STAGE
#pragma unroll
  for (int i = 0; i < 2; ++i) {
    float ls = lsum[i];
    ls += __shfl_xor(ls, 16);
    ls += __shfl_xor(ls, 32);
#pragma unroll
    for (int r = 0; r < 4; ++r) {
      float inv = 1.f / __shfl(ls, 4 * g + r);
      size_t row = mrow0 + 16 * i + 4 * g + r;
#pragma unroll
      for (int jv = 0; jv < 4; ++jv)
        out[row * D_ + dcol0 + 16 * jv + c] = f2bf(oacc[i][jv][r] * inv);
    }
  }
}

// ---------------------------------------------------------------- launch
// Workspace (peak 168.03 MB < 192 MB proven):
//   [0,32)MB xb (reused as ob after QKV gemms) | [32,64) qb | [64,96) kb
//   [96,128) vb | [128,160) vT | [160,168) wqb..wob | [168,+32KB) tables
extern "C" void kernel_launch(void* const* d_in, const int* in_sizes, int n_in,
                              void* d_out, int out_size, void* d_ws, size_t ws_size,
                              hipStream_t stream) {
  const float* x  = (const float*)d_in[0];
  const float* Wq = (const float*)d_in[1];
  const float* bq = (const float*)d_in[2];
  const float* Wk = (const float*)d_in[3];
  const float* bk = (const float*)d_in[4];
  const float* Wv = (const float*)d_in[5];
  const float* bv = (const float*)d_in[6];
  const float* Wo = (const float*)d_in[7];
  const float* bo = (const float*)d_in[8];
  float* out = (float*)d_out;

  char* ws = (char*)d_ws;
  const size_t SZ2 = (size_t)M_TOT * D_ * 2;   // 32 MB
  unsigned short* xb = (unsigned short*)(ws);
  unsigned short* ob = xb;                               // alias: free after QKV gemms
  unsigned short* qb = (unsigned short*)(ws + SZ2);
  unsigned short* kb = (unsigned short*)(ws + 2 * SZ2);
  unsigned short* vb = (unsigned short*)(ws + 3 * SZ2);
  unsigned short* vT = (unsigned short*)(ws + 4 * SZ2);
  unsigned short* wqb = (unsigned short*)(ws + 5 * SZ2);
  unsigned short* wob = wqb + 3 * (size_t)D_ * D_;
  float* cos1 = (float*)(ws + 5 * SZ2 + 4 * (size_t)D_ * D_ * 2);
  float* sin1 = cos1 + S_ * 8;
  float* cos2 = sin1 + S_ * 8;
  float* sin2 = cos2 + 384;

  // 1) tables + x->bf16 + 4 weights->bf16
  prep<<<20514, 256, 0, stream>>>(x, xb, Wq, Wk, Wv, Wo, wqb,
                                  cos1, sin1, cos2, sin2);
  // 2) Q,K,V projections in one launch (grid.y selects W/bias/output)
  gemm_mfma<true><<<dim3(1024, 3), 256, 0, stream>>>(xb, wqb, bq, bk, bv, qb);
  // 3) ropeQ + ropeK + V-transpose in one launch
  postproc<<<69632, 256, 0, stream>>>(qb, kb, vb, vT, cos1, sin1, cos2, sin2);
  // 4) attention
  attn_mfma<<<2048, 256, 0, stream>>>(qb, kb, vT, ob);
  // 5) output projection (f32 out)
  gemm_mfma<false><<<dim3(1024, 1), 256, 0, stream>>>(ob, wob, bo, bo, bo, out);
}

// Round 9
// 471.363 us; speedup vs baseline: 1.0414x; 1.0414x over previous
//
#include <hip/hip_runtime.h>
#include <math.h>

#define B_ 16
#define S_ 1024
#define D_ 1024
#define NH_ 16
#define M_TOT (B_ * S_)

typedef __attribute__((ext_vector_type(8))) short short8v;
typedef __attribute__((ext_vector_type(4))) short short4v;
typedef __attribute__((ext_vector_type(4))) float float4v;
typedef __attribute__((ext_vector_type(4))) unsigned int uint4v;

static __device__ __forceinline__ unsigned short f2bf(float f) {
  union { float f; unsigned u; } x; x.f = f;
  unsigned r = (x.u + 0x7fffu + ((x.u >> 16) & 1u)) >> 16;
  return (unsigned short)r;
}
static __device__ __forceinline__ float bf2f(unsigned short u) {
  union { unsigned u; float f; } x; x.u = ((unsigned)u) << 16;
  return x.f;
}

// pack two f32 -> bf16x2 word, RNE (a -> low half).  Manual f2bf (known-RNE);
// v_cvt_pk_bf16_f32 failed accuracy in round 1 (rounding-mode mismatch).
static __device__ __forceinline__ unsigned pack2bf(float a, float b) {
  return ((unsigned)f2bf(b) << 16) | (unsigned)f2bf(a);
}

// async global->LDS, 16B per lane; LDS dest = wave-uniform base + lane*16 (m104)
static __device__ __forceinline__ void load_lds16(const unsigned short* g, unsigned short* l) {
  __builtin_amdgcn_global_load_lds(
      (const __attribute__((address_space(1))) unsigned int*)g,
      (__attribute__((address_space(3))) unsigned int*)l, 16, 0, 0);
}

// ---------------------------------------------------------------- fused prep
// [0, 16384)        : x f32 -> bf16 (4 elems/thread)
// [16384, 20480)    : 4 weight matrices f32 -> bf16 (4 elems/thread)
// [20480, 20514)    : RoPE tables
__global__ __launch_bounds__(256) void prep(
    const float* __restrict__ x, unsigned short* __restrict__ xb,
    const float* __restrict__ w0, const float* __restrict__ w1,
    const float* __restrict__ w2, const float* __restrict__ w3,
    unsigned short* __restrict__ wdst,
    float* __restrict__ cos1, float* __restrict__ sin1,
    float* __restrict__ cos2, float* __restrict__ sin2) {
  const int bid = blockIdx.x;
  if (bid < 16384) {
    int i = bid * 256 + threadIdx.x;       // < M_TOT*D_/4
    float4 v = ((const float4*)x)[i];
    unsigned short tt[4] = {f2bf(v.x), f2bf(v.y), f2bf(v.z), f2bf(v.w)};
    ((short4v*)xb)[i] = *(short4v*)tt;
  } else if (bid < 20480) {
    int wi = (bid - 16384) * 256 + threadIdx.x;   // < 4*D_*D_/4
    int m = wi >> 18;                             // matrix (block-uniform)
    int i = wi & 262143;
    const float* src = (m == 0) ? w0 : (m == 1) ? w1 : (m == 2) ? w2 : w3;
    float4 v = ((const float4*)src)[i];
    unsigned short tt[4] = {f2bf(v.x), f2bf(v.y), f2bf(v.z), f2bf(v.w)};
    ((short4v*)(wdst + (size_t)m * D_ * D_))[i] = *(short4v*)tt;
  } else {
    int t = (bid - 20480) * 256 + threadIdx.x;
    if (t < S_ * 8) {
      int s = t >> 3, i = t & 7;
      double ang = (double)s * pow(10000.0, -(double)i / 8.0);
      cos1[t] = (float)cos(ang);
      sin1[t] = (float)sin(ang);
    } else if (t < S_ * 8 + 384) {
      int u = t - S_ * 8;
      int p = u / 12, j = u - p * 12;
      double ang = (double)p * pow(10000.0, -(double)j / 12.0);
      cos2[u] = (float)cos(ang);
      sin2[u] = (float)sin(ang);
    }
  }
}

// ---------------------------------------------------------------- bf16 MFMA GEMM
// C[M,1024] = A[M,1024] @ W[1024,1024]^T + bias.  128x128 tile, BK=32.
// Round-7 structure (T4, counted vmcnt), 728 TF: 3 LDS buffers; per step:
// vmcnt(4) waits ONLY the current buffer's 4 loads (next tile's 4 stay in
// flight across the barrier), raw s_barrier (NOT __syncthreads -- compiler
// force-drains vmcnt(0) there), stage k+2, compute.  Drain-to-0 only at end.
// NOTE (round 8): T2 XOR-swizzle eliminated the 12.6M LDS read conflicts but
// REGRESSED 141.6->166.9us -- this coarse-phase structure hides LDS conflicts
// (m230/m252 regime gate) and the pre-swizzled global source slowed the DMA.
// Linear LDS is intentional; do not re-add the swizzle to THIS structure.
// grid.y selects {W, bias, C} (QKV fused in one launch; O uses y=0).
template <bool BF16OUT>
__global__ __launch_bounds__(256) void gemm_mfma(
    const unsigned short* __restrict__ A, const unsigned short* __restrict__ Wall,
    const float* __restrict__ b0, const float* __restrict__ b1,
    const float* __restrict__ b2, void* __restrict__ Cout) {
  __shared__ unsigned short As[3][128 * 32];
  __shared__ unsigned short Bs[3][128 * 32];
  const int y = blockIdx.y;
  const unsigned short* W = Wall + (size_t)y * D_ * D_;
  const float* bias = (y == 0) ? b0 : (y == 1) ? b1 : b2;
  const int t = threadIdx.x;
  const int w = t >> 6, L = t & 63;
  const int c = L & 15, g = L >> 4;
  const int id = blockIdx.x;
  const int xcd = id & 7, slot = id >> 3;
  const int bn = (slot & 7) * 128;
  const int bm = ((slot >> 3) * 8 + xcd) * 128;

  const int srow = w * 32 + (L >> 2);
  const int sko = (L & 3) * 8;
  const unsigned short* gA = A + (size_t)(bm + srow) * D_ + sko;
  const unsigned short* gB = W + (size_t)(bn + srow) * D_ + sko;

  const int wm = (w >> 1) * 64, wn = (w & 1) * 64;

  float4v acc[4][4];
#pragma unroll
  for (int i = 0; i < 4; ++i)
#pragma unroll
    for (int j = 0; j < 4; ++j) acc[i][j] = (float4v){0.f, 0.f, 0.f, 0.f};

#define GS(buf, kt_)                                                   \
  {                                                                    \
    load_lds16(gA + (kt_) * 32, &As[buf][w * 1024]);                   \
    load_lds16(gA + (kt_) * 32 + 16 * D_, &As[buf][w * 1024 + 512]);   \
    load_lds16(gB + (kt_) * 32, &Bs[buf][w * 1024]);                   \
    load_lds16(gB + (kt_) * 32 + 16 * D_, &Bs[buf][w * 1024 + 512]);   \
  }
#define VWAIT4 asm volatile("s_waitcnt vmcnt(4)" ::: "memory")
#define VWAIT0 asm volatile("s_waitcnt vmcnt(0)" ::: "memory")
#define BARRIER asm volatile("s_barrier" ::: "memory")
#define COMPUTE(cur)                                                     \
  {                                                                      \
    short8v af[4], bf[4];                                                \
    _Pragma("unroll")                                                    \
    for (int i = 0; i < 4; ++i)                                          \
      af[i] = *(const short8v*)&As[cur][(wm + 16 * i + c) * 32 + 8 * g]; \
    _Pragma("unroll")                                                    \
    for (int j = 0; j < 4; ++j)                                          \
      bf[j] = *(const short8v*)&Bs[cur][(wn + 16 * j + c) * 32 + 8 * g]; \
    _Pragma("unroll")                                                    \
    for (int i = 0; i < 4; ++i)                                          \
      _Pragma("unroll")                                                  \
      for (int j = 0; j < 4; ++j)                                        \
        acc[i][j] = __builtin_amdgcn_mfma_f32_16x16x32_bf16(             \
            af[i], bf[j], acc[i][j], 0, 0, 0);                           \
  }

  GS(0, 0);          // outstanding 4
  GS(1, 1);          // outstanding 8
#pragma unroll 1
  for (int s = 0; s < 30; s += 3) {
    VWAIT4; BARRIER; GS(2, s + 2); COMPUTE(0);   // step s
    VWAIT4; BARRIER; GS(0, s + 3); COMPUTE(1);   // step s+1
    VWAIT4; BARRIER; GS(1, s + 4); COMPUTE(2);   // step s+2
  }
  VWAIT4; BARRIER; COMPUTE(0);                   // step 30 (k30 in buf0)
  VWAIT0; BARRIER; COMPUTE(1);                   // step 31 (k31 in buf1)
#undef GS
#undef VWAIT4
#undef VWAIT0
#undef BARRIER
#undef COMPUTE
  unsigned short* Cb = (unsigned short*)Cout + (size_t)y * M_TOT * D_;
#pragma unroll
  for (int i = 0; i < 4; ++i)
#pragma unroll
    for (int r = 0; r < 4; ++r) {
      const size_t row = (size_t)bm + wm + 16 * i + 4 * g + r;
#pragma unroll
      for (int j = 0; j < 4; ++j) {
        const int col = bn + wn + 16 * j + c;
        float vv = acc[i][j][r] + bias[col];
        if (BF16OUT)
          Cb[row * D_ + col] = f2bf(vv);
        else
          ((float*)Cout)[row * D_ + col] = vv;
      }
    }
}

// ---------------------------------------------------------------- fused postproc
// [0, 1024)       : RoPE on Q, VECTORIZED: 1 thread per (token, head) owns the
//                   full 64-elem head (128B) -- all rotation pairs (2i,2i+1),
//                   (16+j,28+j), (40+j,52+j) are thread-internal, so loads and
//                   stores are 8x short8v (G13: was 2B-scalar before).
//                   scale 0.125 (EXACT in bf16; log2e-fold banned: 0.125*log2e
//                   not bf16-representable -> round-5 accuracy failure)
// [1024, 2048)    : RoPE on K (scale 1.0), same structure
// [2048, 6144)    : V transpose vb [b][s][hd*64+n] -> vT [b][hd][n][s]
__global__ __launch_bounds__(256) void postproc(
    unsigned short* __restrict__ qb, unsigned short* __restrict__ kbuf,
    const unsigned short* __restrict__ vb, unsigned short* __restrict__ vT,
    const float* __restrict__ cos1, const float* __restrict__ sin1,
    const float* __restrict__ cos2, const float* __restrict__ sin2) {
  __shared__ unsigned short T[64][72];
  const int bid = blockIdx.x;
  if (bid < 2048) {
    const int qk = bid >> 10;                       // 0 = Q, 1 = K
    unsigned short* buf = qk ? kbuf : qb;
    const float scale = qk ? 1.0f : 0.125f;
    const int tid = ((bid & 1023) << 8) + threadIdx.x;   // < 262144
    const int m = tid >> 4, head = tid & 15;
    const int s = m & (S_ - 1);
    const int xx = s & 31, yy = s >> 5;
    unsigned short* p = buf + (size_t)m * D_ + head * 64;

    unsigned short e[64];
#pragma unroll
    for (int v = 0; v < 8; ++v)
      *(short8v*)&e[8 * v] = *(const short8v*)(p + 8 * v);

    // tables (contiguous f32 runs -> vectorizable loads)
    float c1v[8], s1v[8], cxv[12], sxv[12], cyv[12], syv[12];
#pragma unroll
    for (int i = 0; i < 8; ++i) {
      c1v[i] = cos1[s * 8 + i]; s1v[i] = sin1[s * 8 + i];
    }
#pragma unroll
    for (int j = 0; j < 12; ++j) {
      cxv[j] = cos2[xx * 12 + j]; sxv[j] = sin2[xx * 12 + j];
      cyv[j] = cos2[yy * 12 + j]; syv[j] = sin2[yy * 12 + j];
    }
    // 1D latent part: pairs (2i, 2i+1)
#pragma unroll
    for (int i = 0; i < 8; ++i) {
      float a = bf2f(e[2 * i]), b = bf2f(e[2 * i + 1]);
      e[2 * i]     = f2bf((a * c1v[i] - b * s1v[i]) * scale);
      e[2 * i + 1] = f2bf((a * s1v[i] + b * c1v[i]) * scale);
    }
    // 2D spatial part: pairs (16+j, 28+j) via x-angle, (40+j, 52+j) via y-angle
#pragma unroll
    for (int j = 0; j < 12; ++j) {
      float a = bf2f(e[16 + j]), b = bf2f(e[28 + j]);
      e[16 + j] = f2bf((a * cxv[j] - b * sxv[j]) * scale);
      e[28 + j] = f2bf((a * sxv[j] + b * cxv[j]) * scale);
      float a2 = bf2f(e[40 + j]), b2 = bf2f(e[52 + j]);
      e[40 + j] = f2bf((a2 * cyv[j] - b2 * syv[j]) * scale);
      e[52 + j] = f2bf((a2 * syv[j] + b2 * cyv[j]) * scale);
    }
#pragma unroll
    for (int v = 0; v < 8; ++v)
      *(short8v*)(p + 8 * v) = *(short8v*)&e[8 * v];
  } else {
    const int tb = bid - 2048;             // < 4096 = 16 st * 16 hd * 16 b
    const int t = threadIdx.x;
    const int st0 = (tb & 15) * 64;
    const int hd = (tb >> 4) & 15, b = tb >> 8;
    const unsigned short* src = vb + ((size_t)b * S_ + st0) * D_ + hd * 64;
#pragma unroll
    for (int rep = 0; rep < 4; ++rep) {
      int id = t + rep * 256;
      int s = id >> 4, n4 = (id & 15) * 4;
      short4v val = *(const short4v*)(src + (size_t)s * D_ + n4);
      T[n4 + 0][s] = val[0]; T[n4 + 1][s] = val[1];
      T[n4 + 2][s] = val[2]; T[n4 + 3][s] = val[3];
    }
    __syncthreads();
    unsigned short* dst = vT + ((size_t)(b * NH_ + hd) * 64) * S_ + st0;
#pragma unroll
    for (int rep = 0; rep < 2; ++rep) {
      int id = t + rep * 256;
      int n = id >> 3, s8 = (id & 7) * 8;
      unsigned short tmp[8];
#pragma unroll
      for (int u2 = 0; u2 < 8; ++u2) tmp[u2] = T[n][s8 + u2];
      *(short8v*)(dst + (size_t)n * S_ + s8) = *(short8v*)tmp;
    }
  }
}

// ---------------------------------------------------------------- MFMA flash attention
// grid = 2048 linear, swizzled: xcd=id%8, slot=id/8, qt=slot%8,
// pair=(slot/8)*8+xcd.  8 qt-blocks of a pair sit on ONE XCD -> K/V L2-resident.
// Block-shared double-buffered LDS K/V staging (round-4 2x win), swapped QK^T
// with in-register softmax, bpermute P-redistribution.  Unchanged from the
// passing round-4/6/7 kernel.
__global__ __launch_bounds__(256, 4) void attn_mfma(
    const unsigned short* __restrict__ qb, const unsigned short* __restrict__ kb,
    const unsigned short* __restrict__ vT, unsigned short* __restrict__ out) {
  __shared__ unsigned short KV[2][2][4096];   // [dbuf][K/V][64 rows x 64 elems]
  const int t = threadIdx.x;
  const int w = t >> 6;
  const int L = t & 63;
  const int c = L & 15;
  const int g = L >> 4;
  const int id = blockIdx.x;
  const int xcd = id & 7, slot = id >> 3;
  const int qt = slot & 7;
  const int pair = (slot >> 3) * 8 + xcd;
  const int b = pair >> 4, hd = pair & 15;
  const size_t mrow0 = (size_t)b * S_ + qt * 128 + w * 32;
  const int dcol0 = hd * 64;

  // staging lane geometry: lane L writes LDS bytes [seg*1024 + L*16, +16);
  // holds tile row seg*8+(L>>3), col-chunk (L&7); inverse-swizzle the SOURCE
  // col-chunk so reads can XOR with ((row&7)<<4)  (rule #21).
  const int lrow = L >> 3;
  const int lcol = ((L & 7) ^ lrow) * 8;

  // bpermute pull addresses (byte = 4*src_lane)
  const int a_lo = (((L & 16) ? 32 : 0) + c) * 4;
  const int a_hi = a_lo + 64;
  const bool ghi = (L >= 32);
  const int swz = (c & 7) << 3;                   // read-side XOR (elems)

  short8v aq[2][2];
#pragma unroll
  for (int i = 0; i < 2; ++i)
#pragma unroll
    for (int st = 0; st < 2; ++st)
      aq[i][st] = *(const short8v*)(qb + (mrow0 + 16 * i + c) * D_ + dcol0 + 32 * st + 8 * g);

  float4v oacc[2][4];
  float lsum[2] = {0.f, 0.f};
#pragma unroll
  for (int i = 0; i < 2; ++i)
#pragma unroll
    for (int jv = 0; jv < 4; ++jv) oacc[i][jv] = (float4v){0.f, 0.f, 0.f, 0.f};

  const unsigned short* vbase = vT + (size_t)(b * NH_ + hd) * 64 * S_;
  const unsigned short* kbb = kb + (size_t)b * S_ * D_ + dcol0;

#define STAGE(buf, kt_)                                                          \
  {                                                                              \
    _Pragma("unroll")                                                            \
    for (int e = 0; e < 2; ++e) {                                                \
      const int seg = 2 * w + e;                                                 \
      const int row = seg * 8 + lrow;                                            \
      load_lds16(kbb + (size_t)((kt_) * 64 + row) * D_ + lcol,                   \
                 &KV[buf][0][seg * 512]);                                        \
      load_lds16(vbase + (size_t)row * S_ + (kt_) * 64 + lcol,                   \
                 &KV[buf][1][seg * 512]);                                        \
    }                                                                            \
  }

  STAGE(0, 0);
  asm volatile("s_waitcnt vmcnt(0)" ::: "memory");
  __syncthreads();

#pragma unroll 1
  for (int kt = 0; kt < 16; ++kt) {
    const int cur = kt & 1;
    if (kt < 15) STAGE(cur ^ 1, kt + 1);
#pragma unroll
    for (int st = 0; st < 2; ++st) {
      short8v vfh[4];
#pragma unroll
      for (int jv = 0; jv < 4; ++jv)
        vfh[jv] = *(const short8v*)&KV[cur][1][((16 * jv + c) * 64 + st * 32 + 8 * g) ^ swz];
      short8v kfh[2][2];
#pragma unroll
      for (int jl = 0; jl < 2; ++jl)
#pragma unroll
        for (int h = 0; h < 2; ++h)
          kfh[jl][h] = *(const short8v*)&KV[cur][0][((16 * (2 * st + jl) + c) * 64 + h * 32 + 8 * g) ^ swz];
      float4v sacch[2][2];
#pragma unroll
      for (int i = 0; i < 2; ++i)
#pragma unroll
        for (int jl = 0; jl < 2; ++jl) sacch[i][jl] = (float4v){0.f, 0.f, 0.f, 0.f};
      __builtin_amdgcn_s_setprio(1);
#pragma unroll
      for (int jl = 0; jl < 2; ++jl)
#pragma unroll
        for (int i = 0; i < 2; ++i) {
          sacch[i][jl] = __builtin_amdgcn_mfma_f32_16x16x32_bf16(kfh[jl][0], aq[i][0], sacch[i][jl], 0, 0, 0);
          sacch[i][jl] = __builtin_amdgcn_mfma_f32_16x16x32_bf16(kfh[jl][1], aq[i][1], sacch[i][jl], 0, 0, 0);
        }
      __builtin_amdgcn_s_setprio(0);
      // in-register softmax: exp + lane-local row-sum + pack pairs to bf16 (RNE)
      unsigned pkh[2][2][2];
#pragma unroll
      for (int i = 0; i < 2; ++i)
#pragma unroll
        for (int jl = 0; jl < 2; ++jl) {
          float p0 = __expf(sacch[i][jl][0]);
          float p1 = __expf(sacch[i][jl][1]);
          float p2 = __expf(sacch[i][jl][2]);
          float p3 = __expf(sacch[i][jl][3]);
          lsum[i] += (p0 + p1) + (p2 + p3);
          pkh[i][jl][0] = pack2bf(p0, p1);
          pkh[i][jl][1] = pack2bf(p2, p3);
        }
      short8v aph[2];
#pragma unroll
      for (int i = 0; i < 2; ++i) {
        uint4v wv;
#pragma unroll
        for (int q2 = 0; q2 < 4; ++q2) {
          const int addr = (q2 & 2) ? a_hi : a_lo;
          int vlo = __builtin_amdgcn_ds_bpermute(addr, (int)pkh[i][0][q2 & 1]);
          int vhi = __builtin_amdgcn_ds_bpermute(addr, (int)pkh[i][1][q2 & 1]);
          wv[q2] = (unsigned)(ghi ? vhi : vlo);
        }
        aph[i] = *(short8v*)&wv;
      }
      __builtin_amdgcn_s_setprio(1);
#pragma unroll
      for (int jv = 0; jv < 4; ++jv)
#pragma unroll
        for (int i = 0; i < 2; ++i)
          oacc[i][jv] = __builtin_amdgcn_mfma_f32_16x16x32_bf16(aph[i], vfh[jv], oacc[i][jv], 0, 0, 0);
      __builtin_amdgcn_s_setprio(0);
    }
    asm volatile("s_waitcnt vmcnt(0)" ::: "memory");
    __syncthreads();
  }
#undef STAGE
#pragma unroll
  for (int i = 0; i < 2; ++i) {
    float ls = lsum[i];
    ls += __shfl_xor(ls, 16);
    ls += __shfl_xor(ls, 32);
#pragma unroll
    for (int r = 0; r < 4; ++r) {
      float inv = 1.f / __shfl(ls, 4 * g + r);
      size_t row = mrow0 + 16 * i + 4 * g + r;
#pragma unroll
      for (int jv = 0; jv < 4; ++jv)
        out[row * D_ + dcol0 + 16 * jv + c] = f2bf(oacc[i][jv][r] * inv);
    }
  }
}

// ---------------------------------------------------------------- launch
// Workspace (peak 168.03 MB < 192 MB proven):
//   [0,32)MB xb (reused as ob after QKV gemms) | [32,64) qb | [64,96) kb
//   [96,128) vb | [128,160) vT | [160,168) wqb..wob | [168,+32KB) tables
extern "C" void kernel_launch(void* const* d_in, const int* in_sizes, int n_in,
                              void* d_out, int out_size, void* d_ws, size_t ws_size,
                              hipStream_t stream) {
  const float* x  = (const float*)d_in[0];
  const float* Wq = (const float*)d_in[1];
  const float* bq = (const float*)d_in[2];
  const float* Wk = (const float*)d_in[3];
  const float* bk = (const float*)d_in[4];
  const float* Wv = (const float*)d_in[5];
  const float* bv = (const float*)d_in[6];
  const float* Wo = (const float*)d_in[7];
  const float* bo = (const float*)d_in[8];
  float* out = (float*)d_out;

  char* ws = (char*)d_ws;
  const size_t SZ2 = (size_t)M_TOT * D_ * 2;   // 32 MB
  unsigned short* xb = (unsigned short*)(ws);
  unsigned short* ob = xb;                               // alias: free after QKV gemms
  unsigned short* qb = (unsigned short*)(ws + SZ2);
  unsigned short* kb = (unsigned short*)(ws + 2 * SZ2);
  unsigned short* vb = (unsigned short*)(ws + 3 * SZ2);
  unsigned short* vT = (unsigned short*)(ws + 4 * SZ2);
  unsigned short* wqb = (unsigned short*)(ws + 5 * SZ2);
  unsigned short* wob = wqb + 3 * (size_t)D_ * D_;
  float* cos1 = (float*)(ws + 5 * SZ2 + 4 * (size_t)D_ * D_ * 2);
  float* sin1 = cos1 + S_ * 8;
  float* cos2 = sin1 + S_ * 8;
  float* sin2 = cos2 + 384;

  // 1) tables + x->bf16 + 4 weights->bf16
  prep<<<20514, 256, 0, stream>>>(x, xb, Wq, Wk, Wv, Wo, wqb,
                                  cos1, sin1, cos2, sin2);
  // 2) Q,K,V projections in one launch (grid.y selects W/bias/output)
  gemm_mfma<true><<<dim3(1024, 3), 256, 0, stream>>>(xb, wqb, bq, bk, bv, qb);
  // 3) ropeQ + ropeK + V-transpose in one launch (rope now 128B/thread)
  postproc<<<6144, 256, 0, stream>>>(qb, kb, vb, vT, cos1, sin1, cos2, sin2);
  // 4) attention
  attn_mfma<<<2048, 256, 0, stream>>>(qb, kb, vT, ob);
  // 5) output projection (f32 out)
  gemm_mfma<false><<<dim3(1024, 1), 256, 0, stream>>>(ob, wob, bo, bo, bo, out);
}

// Round 10
// 457.579 us; speedup vs baseline: 1.0728x; 1.0301x over previous
//
#include <hip/hip_runtime.h>
#include <math.h>

#define B_ 16
#define S_ 1024
#define D_ 1024
#define NH_ 16
#define M_TOT (B_ * S_)

typedef __attribute__((ext_vector_type(8))) short short8v;
typedef __attribute__((ext_vector_type(4))) short short4v;
typedef __attribute__((ext_vector_type(4))) float float4v;
typedef __attribute__((ext_vector_type(4))) unsigned int uint4v;

static __device__ __forceinline__ unsigned short f2bf(float f) {
  union { float f; unsigned u; } x; x.f = f;
  unsigned r = (x.u + 0x7fffu + ((x.u >> 16) & 1u)) >> 16;
  return (unsigned short)r;
}
static __device__ __forceinline__ float bf2f(unsigned short u) {
  union { unsigned u; float f; } x; x.u = ((unsigned)u) << 16;
  return x.f;
}

// pack two f32 -> bf16x2 word, RNE (a -> low half).  Manual f2bf (known-RNE).
static __device__ __forceinline__ unsigned pack2bf(float a, float b) {
  return ((unsigned)f2bf(b) << 16) | (unsigned)f2bf(a);
}

// HW packed convert f32x2 -> bf16x2 (src0 -> LOW half; order confirmed by the
// round-1 small-error failure signature).  Rounding mode differs from RNE
// (round-1/2 A/B: numerator-only use biased P low -> absmax 9.4e-3).  SAFE
// USAGE (round 10): quantize P with it AND accumulate the softmax denominator
// from the SAME quantized values -- out = sum(p~ v)/sum(p~) is consistent for
// ANY deterministic rounding mode; the bias cancels exactly.
static __device__ __forceinline__ unsigned cvt_pk_bf16(float a, float b) {
  unsigned r;
  asm("v_cvt_pk_bf16_f32 %0, %1, %2" : "=v"(r) : "v"(a), "v"(b));
  return r;
}

// async global->LDS, 16B per lane; LDS dest = wave-uniform base + lane*16 (m104)
static __device__ __forceinline__ void load_lds16(const unsigned short* g, unsigned short* l) {
  __builtin_amdgcn_global_load_lds(
      (const __attribute__((address_space(1))) unsigned int*)g,
      (__attribute__((address_space(3))) unsigned int*)l, 16, 0, 0);
}

// ---------------------------------------------------------------- fused prep
// [0, 16384)        : x f32 -> bf16 (4 elems/thread)
// [16384, 20480)    : 4 weight matrices f32 -> bf16 (4 elems/thread)
// [20480, 20514)    : RoPE tables
__global__ __launch_bounds__(256) void prep(
    const float* __restrict__ x, unsigned short* __restrict__ xb,
    const float* __restrict__ w0, const float* __restrict__ w1,
    const float* __restrict__ w2, const float* __restrict__ w3,
    unsigned short* __restrict__ wdst,
    float* __restrict__ cos1, float* __restrict__ sin1,
    float* __restrict__ cos2, float* __restrict__ sin2) {
  const int bid = blockIdx.x;
  if (bid < 16384) {
    int i = bid * 256 + threadIdx.x;       // < M_TOT*D_/4
    float4 v = ((const float4*)x)[i];
    unsigned short tt[4] = {f2bf(v.x), f2bf(v.y), f2bf(v.z), f2bf(v.w)};
    ((short4v*)xb)[i] = *(short4v*)tt;
  } else if (bid < 20480) {
    int wi = (bid - 16384) * 256 + threadIdx.x;   // < 4*D_*D_/4
    int m = wi >> 18;                             // matrix (block-uniform)
    int i = wi & 262143;
    const float* src = (m == 0) ? w0 : (m == 1) ? w1 : (m == 2) ? w2 : w3;
    float4 v = ((const float4*)src)[i];
    unsigned short tt[4] = {f2bf(v.x), f2bf(v.y), f2bf(v.z), f2bf(v.w)};
    ((short4v*)(wdst + (size_t)m * D_ * D_))[i] = *(short4v*)tt;
  } else {
    int t = (bid - 20480) * 256 + threadIdx.x;
    if (t < S_ * 8) {
      int s = t >> 3, i = t & 7;
      double ang = (double)s * pow(10000.0, -(double)i / 8.0);
      cos1[t] = (float)cos(ang);
      sin1[t] = (float)sin(ang);
    } else if (t < S_ * 8 + 384) {
      int u = t - S_ * 8;
      int p = u / 12, j = u - p * 12;
      double ang = (double)p * pow(10000.0, -(double)j / 12.0);
      cos2[u] = (float)cos(ang);
      sin2[u] = (float)sin(ang);
    }
  }
}

// ---------------------------------------------------------------- bf16 MFMA GEMM
// C[M,1024] = A[M,1024] @ W[1024,1024]^T + bias.  128x128 tile, BK=32.
// Round-7 structure (T4, counted vmcnt), 730 TF: 3 LDS buffers; per step:
// vmcnt(4) waits ONLY the current buffer's 4 loads (next tile's 4 stay in
// flight across the barrier), raw s_barrier (NOT __syncthreads -- compiler
// force-drains vmcnt(0) there), stage k+2, compute.  Drain-to-0 only at end.
// NOTE (round 8): T2 XOR-swizzle eliminated the 12.6M LDS read conflicts but
// REGRESSED 141.6->166.9us -- this coarse-phase structure hides LDS conflicts
// (m230/m252 regime gate) and the pre-swizzled global source slowed the DMA.
// Linear LDS is intentional; do not re-add the swizzle to THIS structure.
// grid.y selects {W, bias, C} (QKV fused in one launch; O uses y=0).
template <bool BF16OUT>
__global__ __launch_bounds__(256) void gemm_mfma(
    const unsigned short* __restrict__ A, const unsigned short* __restrict__ Wall,
    const float* __restrict__ b0, const float* __restrict__ b1,
    const float* __restrict__ b2, void* __restrict__ Cout) {
  __shared__ unsigned short As[3][128 * 32];
  __shared__ unsigned short Bs[3][128 * 32];
  const int y = blockIdx.y;
  const unsigned short* W = Wall + (size_t)y * D_ * D_;
  const float* bias = (y == 0) ? b0 : (y == 1) ? b1 : b2;
  const int t = threadIdx.x;
  const int w = t >> 6, L = t & 63;
  const int c = L & 15, g = L >> 4;
  const int id = blockIdx.x;
  const int xcd = id & 7, slot = id >> 3;
  const int bn = (slot & 7) * 128;
  const int bm = ((slot >> 3) * 8 + xcd) * 128;

  const int srow = w * 32 + (L >> 2);
  const int sko = (L & 3) * 8;
  const unsigned short* gA = A + (size_t)(bm + srow) * D_ + sko;
  const unsigned short* gB = W + (size_t)(bn + srow) * D_ + sko;

  const int wm = (w >> 1) * 64, wn = (w & 1) * 64;

  float4v acc[4][4];
#pragma unroll
  for (int i = 0; i < 4; ++i)
#pragma unroll
    for (int j = 0; j < 4; ++j) acc[i][j] = (float4v){0.f, 0.f, 0.f, 0.f};

#define GS(buf, kt_)                                                   \
  {                                                                    \
    load_lds16(gA + (kt_) * 32, &As[buf][w * 1024]);                   \
    load_lds16(gA + (kt_) * 32 + 16 * D_, &As[buf][w * 1024 + 512]);   \
    load_lds16(gB + (kt_) * 32, &Bs[buf][w * 1024]);                   \
    load_lds16(gB + (kt_) * 32 + 16 * D_, &Bs[buf][w * 1024 + 512]);   \
  }
#define VWAIT4 asm volatile("s_waitcnt vmcnt(4)" ::: "memory")
#define VWAIT0 asm volatile("s_waitcnt vmcnt(0)" ::: "memory")
#define BARRIER asm volatile("s_barrier" ::: "memory")
#define COMPUTE(cur)                                                     \
  {                                                                      \
    short8v af[4], bf[4];                                                \
    _Pragma("unroll")                                                    \
    for (int i = 0; i < 4; ++i)                                          \
      af[i] = *(const short8v*)&As[cur][(wm + 16 * i + c) * 32 + 8 * g]; \
    _Pragma("unroll")                                                    \
    for (int j = 0; j < 4; ++j)                                          \
      bf[j] = *(const short8v*)&Bs[cur][(wn + 16 * j + c) * 32 + 8 * g]; \
    _Pragma("unroll")                                                    \
    for (int i = 0; i < 4; ++i)                                          \
      _Pragma("unroll")                                                  \
      for (int j = 0; j < 4; ++j)                                        \
        acc[i][j] = __builtin_amdgcn_mfma_f32_16x16x32_bf16(             \
            af[i], bf[j], acc[i][j], 0, 0, 0);                           \
  }

  GS(0, 0);          // outstanding 4
  GS(1, 1);          // outstanding 8
#pragma unroll 1
  for (int s = 0; s < 30; s += 3) {
    VWAIT4; BARRIER; GS(2, s + 2); COMPUTE(0);   // step s
    VWAIT4; BARRIER; GS(0, s + 3); COMPUTE(1);   // step s+1
    VWAIT4; BARRIER; GS(1, s + 4); COMPUTE(2);   // step s+2
  }
  VWAIT4; BARRIER; COMPUTE(0);                   // step 30 (k30 in buf0)
  VWAIT0; BARRIER; COMPUTE(1);                   // step 31 (k31 in buf1)
#undef GS
#undef VWAIT4
#undef VWAIT0
#undef BARRIER
#undef COMPUTE
  unsigned short* Cb = (unsigned short*)Cout + (size_t)y * M_TOT * D_;
#pragma unroll
  for (int i = 0; i < 4; ++i)
#pragma unroll
    for (int r = 0; r < 4; ++r) {
      const size_t row = (size_t)bm + wm + 16 * i + 4 * g + r;
#pragma unroll
      for (int j = 0; j < 4; ++j) {
        const int col = bn + wn + 16 * j + c;
        float vv = acc[i][j][r] + bias[col];
        if (BF16OUT)
          Cb[row * D_ + col] = f2bf(vv);
        else
          ((float*)Cout)[row * D_ + col] = vv;
      }
    }
}

// ---------------------------------------------------------------- fused postproc
// [0, 1024)       : RoPE on Q, vectorized: 1 thread per (token, head) owns the
//                   full 64-elem head (128B); all rotation pairs thread-internal.
//                   scale 0.125 (EXACT in bf16; log2e-fold banned: 0.125*log2e
//                   not bf16-representable -> round-5 accuracy failure)
// [1024, 2048)    : RoPE on K (scale 1.0), same structure
// [2048, 6144)    : V transpose vb [b][s][hd*64+n] -> vT [b][hd][n][s]
__global__ __launch_bounds__(256) void postproc(
    unsigned short* __restrict__ qb, unsigned short* __restrict__ kbuf,
    const unsigned short* __restrict__ vb, unsigned short* __restrict__ vT,
    const float* __restrict__ cos1, const float* __restrict__ sin1,
    const float* __restrict__ cos2, const float* __restrict__ sin2) {
  __shared__ unsigned short T[64][72];
  const int bid = blockIdx.x;
  if (bid < 2048) {
    const int qk = bid >> 10;                       // 0 = Q, 1 = K
    unsigned short* buf = qk ? kbuf : qb;
    const float scale = qk ? 1.0f : 0.125f;
    const int tid = ((bid & 1023) << 8) + threadIdx.x;   // < 262144
    const int m = tid >> 4, head = tid & 15;
    const int s = m & (S_ - 1);
    const int xx = s & 31, yy = s >> 5;
    unsigned short* p = buf + (size_t)m * D_ + head * 64;

    unsigned short e[64];
#pragma unroll
    for (int v = 0; v < 8; ++v)
      *(short8v*)&e[8 * v] = *(const short8v*)(p + 8 * v);

    float c1v[8], s1v[8], cxv[12], sxv[12], cyv[12], syv[12];
#pragma unroll
    for (int i = 0; i < 8; ++i) {
      c1v[i] = cos1[s * 8 + i]; s1v[i] = sin1[s * 8 + i];
    }
#pragma unroll
    for (int j = 0; j < 12; ++j) {
      cxv[j] = cos2[xx * 12 + j]; sxv[j] = sin2[xx * 12 + j];
      cyv[j] = cos2[yy * 12 + j]; syv[j] = sin2[yy * 12 + j];
    }
#pragma unroll
    for (int i = 0; i < 8; ++i) {
      float a = bf2f(e[2 * i]), b = bf2f(e[2 * i + 1]);
      e[2 * i]     = f2bf((a * c1v[i] - b * s1v[i]) * scale);
      e[2 * i + 1] = f2bf((a * s1v[i] + b * c1v[i]) * scale);
    }
#pragma unroll
    for (int j = 0; j < 12; ++j) {
      float a = bf2f(e[16 + j]), b = bf2f(e[28 + j]);
      e[16 + j] = f2bf((a * cxv[j] - b * sxv[j]) * scale);
      e[28 + j] = f2bf((a * sxv[j] + b * cxv[j]) * scale);
      float a2 = bf2f(e[40 + j]), b2 = bf2f(e[52 + j]);
      e[40 + j] = f2bf((a2 * cyv[j] - b2 * syv[j]) * scale);
      e[52 + j] = f2bf((a2 * syv[j] + b2 * cyv[j]) * scale);
    }
#pragma unroll
    for (int v = 0; v < 8; ++v)
      *(short8v*)(p + 8 * v) = *(short8v*)&e[8 * v];
  } else {
    const int tb = bid - 2048;             // < 4096 = 16 st * 16 hd * 16 b
    const int t = threadIdx.x;
    const int st0 = (tb & 15) * 64;
    const int hd = (tb >> 4) & 15, b = tb >> 8;
    const unsigned short* src = vb + ((size_t)b * S_ + st0) * D_ + hd * 64;
#pragma unroll
    for (int rep = 0; rep < 4; ++rep) {
      int id = t + rep * 256;
      int s = id >> 4, n4 = (id & 15) * 4;
      short4v val = *(const short4v*)(src + (size_t)s * D_ + n4);
      T[n4 + 0][s] = val[0]; T[n4 + 1][s] = val[1];
      T[n4 + 2][s] = val[2]; T[n4 + 3][s] = val[3];
    }
    __syncthreads();
    unsigned short* dst = vT + ((size_t)(b * NH_ + hd) * 64) * S_ + st0;
#pragma unroll
    for (int rep = 0; rep < 2; ++rep) {
      int id = t + rep * 256;
      int n = id >> 3, s8 = (id & 7) * 8;
      unsigned short tmp[8];
#pragma unroll
      for (int u2 = 0; u2 < 8; ++u2) tmp[u2] = T[n][s8 + u2];
      *(short8v*)(dst + (size_t)n * S_ + s8) = *(short8v*)tmp;
    }
  }
}

// ---------------------------------------------------------------- MFMA flash attention
// grid = 2048 linear, swizzled: xcd=id%8, slot=id/8, qt=slot%8,
// pair=(slot/8)*8+xcd.  8 qt-blocks of a pair sit on ONE XCD -> K/V L2-resident.
// Block-shared double-buffered LDS K/V staging (round-4 2x win), swapped QK^T
// with in-register softmax, bpermute P-redistribution.
// Round 10: truncation-consistent cvt_pk softmax -- P quantized via the HW
// v_cvt_pk_bf16_f32 AND the denominator summed from the SAME quantized values
// (bias cancels for any deterministic rounding; cuts ~25% of the VALU stream
// that dominates at 54% VALUBusy).
__global__ __launch_bounds__(256, 4) void attn_mfma(
    const unsigned short* __restrict__ qb, const unsigned short* __restrict__ kb,
    const unsigned short* __restrict__ vT, unsigned short* __restrict__ out) {
  __shared__ unsigned short KV[2][2][4096];   // [dbuf][K/V][64 rows x 64 elems]
  const int t = threadIdx.x;
  const int w = t >> 6;
  const int L = t & 63;
  const int c = L & 15;
  const int g = L >> 4;
  const int id = blockIdx.x;
  const int xcd = id & 7, slot = id >> 3;
  const int qt = slot & 7;
  const int pair = (slot >> 3) * 8 + xcd;
  const int b = pair >> 4, hd = pair & 15;
  const size_t mrow0 = (size_t)b * S_ + qt * 128 + w * 32;
  const int dcol0 = hd * 64;

  // staging lane geometry: lane L writes LDS bytes [seg*1024 + L*16, +16);
  // holds tile row seg*8+(L>>3), col-chunk (L&7); inverse-swizzle the SOURCE
  // col-chunk so reads can XOR with ((row&7)<<4)  (rule #21).
  const int lrow = L >> 3;
  const int lcol = ((L & 7) ^ lrow) * 8;

  // bpermute pull addresses (byte = 4*src_lane)
  const int a_lo = (((L & 16) ? 32 : 0) + c) * 4;
  const int a_hi = a_lo + 64;
  const bool ghi = (L >= 32);
  const int swz = (c & 7) << 3;                   // read-side XOR (elems)

  short8v aq[2][2];
#pragma unroll
  for (int i = 0; i < 2; ++i)
#pragma unroll
    for (int st = 0; st < 2; ++st)
      aq[i][st] = *(const short8v*)(qb + (mrow0 + 16 * i + c) * D_ + dcol0 + 32 * st + 8 * g);

  float4v oacc[2][4];
  float lsum[2] = {0.f, 0.f};
#pragma unroll
  for (int i = 0; i < 2; ++i)
#pragma unroll
    for (int jv = 0; jv < 4; ++jv) oacc[i][jv] = (float4v){0.f, 0.f, 0.f, 0.f};

  const unsigned short* vbase = vT + (size_t)(b * NH_ + hd) * 64 * S_;
  const unsigned short* kbb = kb + (size_t)b * S_ * D_ + dcol0;

#define STAGE(buf, kt_)                                                          \
  {                                                                              \
    _Pragma("unroll")                                                            \
    for (int e = 0; e < 2; ++e) {                                                \
      const int seg = 2 * w + e;                                                 \
      const int row = seg * 8 + lrow;                                            \
      load_lds16(kbb + (size_t)((kt_) * 64 + row) * D_ + lcol,                   \
                 &KV[buf][0][seg * 512]);                                        \
      load_lds16(vbase + (size_t)row * S_ + (kt_) * 64 + lcol,                   \
                 &KV[buf][1][seg * 512]);                                        \
    }                                                                            \
  }

  STAGE(0, 0);
  asm volatile("s_waitcnt vmcnt(0)" ::: "memory");
  __syncthreads();

#pragma unroll 1
  for (int kt = 0; kt < 16; ++kt) {
    const int cur = kt & 1;
    if (kt < 15) STAGE(cur ^ 1, kt + 1);
#pragma unroll
    for (int st = 0; st < 2; ++st) {
      short8v vfh[4];
#pragma unroll
      for (int jv = 0; jv < 4; ++jv)
        vfh[jv] = *(const short8v*)&KV[cur][1][((16 * jv + c) * 64 + st * 32 + 8 * g) ^ swz];
      short8v kfh[2][2];
#pragma unroll
      for (int jl = 0; jl < 2; ++jl)
#pragma unroll
        for (int h = 0; h < 2; ++h)
          kfh[jl][h] = *(const short8v*)&KV[cur][0][((16 * (2 * st + jl) + c) * 64 + h * 32 + 8 * g) ^ swz];
      float4v sacch[2][2];
#pragma unroll
      for (int i = 0; i < 2; ++i)
#pragma unroll
        for (int jl = 0; jl < 2; ++jl) sacch[i][jl] = (float4v){0.f, 0.f, 0.f, 0.f};
      __builtin_amdgcn_s_setprio(1);
#pragma unroll
      for (int jl = 0; jl < 2; ++jl)
#pragma unroll
        for (int i = 0; i < 2; ++i) {
          sacch[i][jl] = __builtin_amdgcn_mfma_f32_16x16x32_bf16(kfh[jl][0], aq[i][0], sacch[i][jl], 0, 0, 0);
          sacch[i][jl] = __builtin_amdgcn_mfma_f32_16x16x32_bf16(kfh[jl][1], aq[i][1], sacch[i][jl], 0, 0, 0);
        }
      __builtin_amdgcn_s_setprio(0);
      // softmax: exp -> HW packed bf16 convert; denominator from the SAME
      // quantized values (truncation-consistent -> rounding bias cancels)
      unsigned pkh[2][2][2];
#pragma unroll
      for (int i = 0; i < 2; ++i)
#pragma unroll
        for (int jl = 0; jl < 2; ++jl) {
          float p0 = __expf(sacch[i][jl][0]);
          float p1 = __expf(sacch[i][jl][1]);
          float p2 = __expf(sacch[i][jl][2]);
          float p3 = __expf(sacch[i][jl][3]);
          const unsigned w0 = cvt_pk_bf16(p0, p1);
          const unsigned w1 = cvt_pk_bf16(p2, p3);
          pkh[i][jl][0] = w0;
          pkh[i][jl][1] = w1;
          union { unsigned u; float f; } t0, t1, t2, t3;
          t0.u = w0 << 16; t1.u = w0 & 0xffff0000u;
          t2.u = w1 << 16; t3.u = w1 & 0xffff0000u;
          lsum[i] += (t0.f + t1.f) + (t2.f + t3.f);
        }
      short8v aph[2];
#pragma unroll
      for (int i = 0; i < 2; ++i) {
        uint4v wv;
#pragma unroll
        for (int q2 = 0; q2 < 4; ++q2) {
          const int addr = (q2 & 2) ? a_hi : a_lo;
          int vlo = __builtin_amdgcn_ds_bpermute(addr, (int)pkh[i][0][q2 & 1]);
          int vhi = __builtin_amdgcn_ds_bpermute(addr, (int)pkh[i][1][q2 & 1]);
          wv[q2] = (unsigned)(ghi ? vhi : vlo);
        }
        aph[i] = *(short8v*)&wv;
      }
      __builtin_amdgcn_s_setprio(1);
#pragma unroll
      for (int jv = 0; jv < 4; ++jv)
#pragma unroll
        for (int i = 0; i < 2; ++i)
          oacc[i][jv] = __builtin_amdgcn_mfma_f32_16x16x32_bf16(aph[i], vfh[jv], oacc[i][jv], 0, 0, 0);
      __builtin_amdgcn_s_setprio(0);
    }
    asm volatile("s_waitcnt vmcnt(0)" ::: "memory");
    __syncthreads();
  }
#undef STAGE
#pragma unroll
  for (int i = 0; i < 2; ++i) {
    float ls = lsum[i];
    ls += __shfl_xor(ls, 16);
    ls += __shfl_xor(ls, 32);
#pragma unroll
    for (int r = 0; r < 4; ++r) {
      float inv = 1.f / __shfl(ls, 4 * g + r);
      size_t row = mrow0 + 16 * i + 4 * g + r;
#pragma unroll
      for (int jv = 0; jv < 4; ++jv)
        out[row * D_ + dcol0 + 16 * jv + c] = f2bf(oacc[i][jv][r] * inv);
    }
  }
}

// ---------------------------------------------------------------- launch
// Workspace (peak 168.03 MB < 192 MB proven):
//   [0,32)MB xb (reused as ob after QKV gemms) | [32,64) qb | [64,96) kb
//   [96,128) vb | [128,160) vT | [160,168) wqb..wob | [168,+32KB) tables
extern "C" void kernel_launch(void* const* d_in, const int* in_sizes, int n_in,
                              void* d_out, int out_size, void* d_ws, size_t ws_size,
                              hipStream_t stream) {
  const float* x  = (const float*)d_in[0];
  const float* Wq = (const float*)d_in[1];
  const float* bq = (const float*)d_in[2];
  const float* Wk = (const float*)d_in[3];
  const float* bk = (const float*)d_in[4];
  const float* Wv = (const float*)d_in[5];
  const float* bv = (const float*)d_in[6];
  const float* Wo = (const float*)d_in[7];
  const float* bo = (const float*)d_in[8];
  float* out = (float*)d_out;

  char* ws = (char*)d_ws;
  const size_t SZ2 = (size_t)M_TOT * D_ * 2;   // 32 MB
  unsigned short* xb = (unsigned short*)(ws);
  unsigned short* ob = xb;                               // alias: free after QKV gemms
  unsigned short* qb = (unsigned short*)(ws + SZ2);
  unsigned short* kb = (unsigned short*)(ws + 2 * SZ2);
  unsigned short* vb = (unsigned short*)(ws + 3 * SZ2);
  unsigned short* vT = (unsigned short*)(ws + 4 * SZ2);
  unsigned short* wqb = (unsigned short*)(ws + 5 * SZ2);
  unsigned short* wob = wqb + 3 * (size_t)D_ * D_;
  float* cos1 = (float*)(ws + 5 * SZ2 + 4 * (size_t)D_ * D_ * 2);
  float* sin1 = cos1 + S_ * 8;
  float* cos2 = sin1 + S_ * 8;
  float* sin2 = cos2 + 384;

  // 1) tables + x->bf16 + 4 weights->bf16
  prep<<<20514, 256, 0, stream>>>(x, xb, Wq, Wk, Wv, Wo, wqb,
                                  cos1, sin1, cos2, sin2);
  // 2) Q,K,V projections in one launch (grid.y selects W/bias/output)
  gemm_mfma<true><<<dim3(1024, 3), 256, 0, stream>>>(xb, wqb, bq, bk, bv, qb);
  // 3) ropeQ + ropeK + V-transpose in one launch
  postproc<<<6144, 256, 0, stream>>>(qb, kb, vb, vT, cos1, sin1, cos2, sin2);
  // 4) attention
  attn_mfma<<<2048, 256, 0, stream>>>(qb, kb, vT, ob);
  // 5) output projection (f32 out)
  gemm_mfma<false><<<dim3(1024, 1), 256, 0, stream>>>(ob, wob, bo, bo, bo, out);
}

// Round 11
// 426.524 us; speedup vs baseline: 1.1509x; 1.0728x over previous
//
#include <hip/hip_runtime.h>
#include <math.h>

#define B_ 16
#define S_ 1024
#define D_ 1024
#define NH_ 16
#define M_TOT (B_ * S_)

typedef __attribute__((ext_vector_type(8))) short short8v;
typedef __attribute__((ext_vector_type(4))) short short4v;
typedef __attribute__((ext_vector_type(4))) float float4v;
typedef __attribute__((ext_vector_type(4))) unsigned int uint4v;

static __device__ __forceinline__ unsigned short f2bf(float f) {
  union { float f; unsigned u; } x; x.f = f;
  unsigned r = (x.u + 0x7fffu + ((x.u >> 16) & 1u)) >> 16;
  return (unsigned short)r;
}
static __device__ __forceinline__ float bf2f(unsigned short u) {
  union { unsigned u; float f; } x; x.u = ((unsigned)u) << 16;
  return x.f;
}

// HW packed convert f32x2 -> bf16x2 (src0 -> LOW half).  Rounding differs from
// RNE; SAFE only when numerator and denominator share the quantization
// (round-10 proven: truncation-consistent softmax, bias cancels).
static __device__ __forceinline__ unsigned cvt_pk_bf16(float a, float b) {
  unsigned r;
  asm("v_cvt_pk_bf16_f32 %0, %1, %2" : "=v"(r) : "v"(a), "v"(b));
  return r;
}

// async global->LDS, 16B per lane; LDS dest = wave-uniform base + lane*16 (m104)
static __device__ __forceinline__ void load_lds16(const unsigned short* g, unsigned short* l) {
  __builtin_amdgcn_global_load_lds(
      (const __attribute__((address_space(1))) unsigned int*)g,
      (__attribute__((address_space(3))) unsigned int*)l, 16, 0, 0);
}

// ---------------------------------------------------------------- fused prep
// [0, 16384)        : x f32 -> bf16 (4 elems/thread)
// [16384, 20480)    : 4 weight matrices f32 -> bf16 (4 elems/thread)
// [20480, 20514)    : RoPE tables
__global__ __launch_bounds__(256) void prep(
    const float* __restrict__ x, unsigned short* __restrict__ xb,
    const float* __restrict__ w0, const float* __restrict__ w1,
    const float* __restrict__ w2, const float* __restrict__ w3,
    unsigned short* __restrict__ wdst,
    float* __restrict__ cos1, float* __restrict__ sin1,
    float* __restrict__ cos2, float* __restrict__ sin2) {
  const int bid = blockIdx.x;
  if (bid < 16384) {
    int i = bid * 256 + threadIdx.x;       // < M_TOT*D_/4
    float4 v = ((const float4*)x)[i];
    unsigned short tt[4] = {f2bf(v.x), f2bf(v.y), f2bf(v.z), f2bf(v.w)};
    ((short4v*)xb)[i] = *(short4v*)tt;
  } else if (bid < 20480) {
    int wi = (bid - 16384) * 256 + threadIdx.x;   // < 4*D_*D_/4
    int m = wi >> 18;                             // matrix (block-uniform)
    int i = wi & 262143;
    const float* src = (m == 0) ? w0 : (m == 1) ? w1 : (m == 2) ? w2 : w3;
    float4 v = ((const float4*)src)[i];
    unsigned short tt[4] = {f2bf(v.x), f2bf(v.y), f2bf(v.z), f2bf(v.w)};
    ((short4v*)(wdst + (size_t)m * D_ * D_))[i] = *(short4v*)tt;
  } else {
    int t = (bid - 20480) * 256 + threadIdx.x;
    if (t < S_ * 8) {
      int s = t >> 3, i = t & 7;
      double ang = (double)s * pow(10000.0, -(double)i / 8.0);
      cos1[t] = (float)cos(ang);
      sin1[t] = (float)sin(ang);
    } else if (t < S_ * 8 + 384) {
      int u = t - S_ * 8;
      int p = u / 12, j = u - p * 12;
      double ang = (double)p * pow(10000.0, -(double)j / 12.0);
      cos2[u] = (float)cos(ang);
      sin2[u] = (float)sin(ang);
    }
  }
}

// ---------------------------------------------------------------- bf16 MFMA GEMM
// C[M,1024] = A[M,1024] @ W[1024,1024]^T + bias.
// Round-11 geometry: 128x256 tile, 512 threads = 8 waves (2M x 4N), per-wave
// 64x64 output (fragment math identical to the proven 128x128 version), BK=32.
// Sync skeleton UNCHANGED from round 7 (T4 counted vmcnt, 3 LDS buffers, raw
// s_barrier): per step VWAIT3 (own 3 loads of cur buffer retired) BEFORE the
// barrier -> after barrier ALL waves' cur loads retired; stage k+2; compute.
// Wins vs 128x128: staging insts/FLOP x0.75, A HBM traffic halved (A-panel
// read by 4 n-blocks not 8), LDS 72KB -> 2 blocks/CU = 16 waves/CU (was ~10).
// NOTE (round 8): T2 XOR-swizzle REGRESSED this coarse-phase structure
// (m230/m252 regime gate) -- linear LDS is intentional.
// grid.y selects {W, bias, C} (QKV fused in one launch; O uses y=0).
template <bool BF16OUT>
__global__ __launch_bounds__(512, 4) void gemm_mfma(
    const unsigned short* __restrict__ A, const unsigned short* __restrict__ Wall,
    const float* __restrict__ b0, const float* __restrict__ b1,
    const float* __restrict__ b2, void* __restrict__ Cout) {
  __shared__ unsigned short As[3][128 * 32];   // 8 KB / buf
  __shared__ unsigned short Bs[3][256 * 32];   // 16 KB / buf
  const int y = blockIdx.y;
  const unsigned short* W = Wall + (size_t)y * D_ * D_;
  const float* bias = (y == 0) ? b0 : (y == 1) ? b1 : b2;
  const int t = threadIdx.x;            // 0..511
  const int wid = t >> 6, L = t & 63;
  const int c = L & 15, g = L >> 4;
  const int id = blockIdx.x;            // 0..511
  const int xcd = id & 7, slot = id >> 3;
  const int bn = (slot & 3) * 256;      // 4 n-blocks
  const int bm = ((slot >> 2) * 8 + xcd) * 128;   // 128 m-blocks (512%8==0 ✓)

  // staging: thread t owns (row = t>>2, 16B-chunk = t&3); A 1 load, B 2 loads.
  // LDS dest per wave = base + wid*512 elems (lane L slot = +8L, linear ✓).
  const unsigned short* gA = A + (size_t)(bm + (t >> 2)) * D_ + (t & 3) * 8;
  const unsigned short* gB = W + (size_t)(bn + (t >> 2)) * D_ + (t & 3) * 8;

  const int wm = (wid >> 2) * 64, wn = (wid & 3) * 64;

  float4v acc[4][4];
#pragma unroll
  for (int i = 0; i < 4; ++i)
#pragma unroll
    for (int j = 0; j < 4; ++j) acc[i][j] = (float4v){0.f, 0.f, 0.f, 0.f};

#define GS(buf, kt_)                                                     \
  {                                                                      \
    load_lds16(gA + (kt_) * 32, &As[buf][wid * 512]);                    \
    load_lds16(gB + (kt_) * 32, &Bs[buf][wid * 512]);                    \
    load_lds16(gB + (kt_) * 32 + 128 * D_, &Bs[buf][wid * 512 + 4096]);  \
  }
#define VWAIT3 asm volatile("s_waitcnt vmcnt(3)" ::: "memory")
#define VWAIT0 asm volatile("s_waitcnt vmcnt(0)" ::: "memory")
#define BARRIER asm volatile("s_barrier" ::: "memory")
#define COMPUTE(cur)                                                     \
  {                                                                      \
    short8v af[4], bf[4];                                                \
    _Pragma("unroll")                                                    \
    for (int i = 0; i < 4; ++i)                                          \
      af[i] = *(const short8v*)&As[cur][(wm + 16 * i + c) * 32 + 8 * g]; \
    _Pragma("unroll")                                                    \
    for (int j = 0; j < 4; ++j)                                          \
      bf[j] = *(const short8v*)&Bs[cur][(wn + 16 * j + c) * 32 + 8 * g]; \
    _Pragma("unroll")                                                    \
    for (int i = 0; i < 4; ++i)                                          \
      _Pragma("unroll")                                                  \
      for (int j = 0; j < 4; ++j)                                        \
        acc[i][j] = __builtin_amdgcn_mfma_f32_16x16x32_bf16(             \
            af[i], bf[j], acc[i][j], 0, 0, 0);                           \
  }

  GS(0, 0);          // outstanding 3
  GS(1, 1);          // outstanding 6
#pragma unroll 1
  for (int s = 0; s < 30; s += 3) {
    VWAIT3; BARRIER; GS(2, s + 2); COMPUTE(0);   // step s
    VWAIT3; BARRIER; GS(0, s + 3); COMPUTE(1);   // step s+1
    VWAIT3; BARRIER; GS(1, s + 4); COMPUTE(2);   // step s+2
  }
  VWAIT3; BARRIER; COMPUTE(0);                   // step 30 (k30 in buf0)
  VWAIT0; BARRIER; COMPUTE(1);                   // step 31 (k31 in buf1)
#undef GS
#undef VWAIT3
#undef VWAIT0
#undef BARRIER
#undef COMPUTE
  unsigned short* Cb = (unsigned short*)Cout + (size_t)y * M_TOT * D_;
#pragma unroll
  for (int i = 0; i < 4; ++i)
#pragma unroll
    for (int r = 0; r < 4; ++r) {
      const size_t row = (size_t)bm + wm + 16 * i + 4 * g + r;
#pragma unroll
      for (int j = 0; j < 4; ++j) {
        const int col = bn + wn + 16 * j + c;
        float vv = acc[i][j][r] + bias[col];
        if (BF16OUT)
          Cb[row * D_ + col] = f2bf(vv);
        else
          ((float*)Cout)[row * D_ + col] = vv;
      }
    }
}

// ---------------------------------------------------------------- fused postproc
// [0, 1024)       : RoPE on Q, vectorized: 1 thread per (token, head) owns the
//                   full 64-elem head (128B); all rotation pairs thread-internal.
//                   scale 0.125 (EXACT in bf16; log2e-fold banned: 0.125*log2e
//                   not bf16-representable -> round-5 accuracy failure)
// [1024, 2048)    : RoPE on K (scale 1.0), same structure
// [2048, 6144)    : V transpose vb [b][s][hd*64+n] -> vT [b][hd][n][s]
__global__ __launch_bounds__(256) void postproc(
    unsigned short* __restrict__ qb, unsigned short* __restrict__ kbuf,
    const unsigned short* __restrict__ vb, unsigned short* __restrict__ vT,
    const float* __restrict__ cos1, const float* __restrict__ sin1,
    const float* __restrict__ cos2, const float* __restrict__ sin2) {
  __shared__ unsigned short T[64][72];
  const int bid = blockIdx.x;
  if (bid < 2048) {
    const int qk = bid >> 10;                       // 0 = Q, 1 = K
    unsigned short* buf = qk ? kbuf : qb;
    const float scale = qk ? 1.0f : 0.125f;
    const int tid = ((bid & 1023) << 8) + threadIdx.x;   // < 262144
    const int m = tid >> 4, head = tid & 15;
    const int s = m & (S_ - 1);
    const int xx = s & 31, yy = s >> 5;
    unsigned short* p = buf + (size_t)m * D_ + head * 64;

    unsigned short e[64];
#pragma unroll
    for (int v = 0; v < 8; ++v)
      *(short8v*)&e[8 * v] = *(const short8v*)(p + 8 * v);

    float c1v[8], s1v[8], cxv[12], sxv[12], cyv[12], syv[12];
#pragma unroll
    for (int i = 0; i < 8; ++i) {
      c1v[i] = cos1[s * 8 + i]; s1v[i] = sin1[s * 8 + i];
    }
#pragma unroll
    for (int j = 0; j < 12; ++j) {
      cxv[j] = cos2[xx * 12 + j]; sxv[j] = sin2[xx * 12 + j];
      cyv[j] = cos2[yy * 12 + j]; syv[j] = sin2[yy * 12 + j];
    }
#pragma unroll
    for (int i = 0; i < 8; ++i) {
      float a = bf2f(e[2 * i]), b = bf2f(e[2 * i + 1]);
      e[2 * i]     = f2bf((a * c1v[i] - b * s1v[i]) * scale);
      e[2 * i + 1] = f2bf((a * s1v[i] + b * c1v[i]) * scale);
    }
#pragma unroll
    for (int j = 0; j < 12; ++j) {
      float a = bf2f(e[16 + j]), b = bf2f(e[28 + j]);
      e[16 + j] = f2bf((a * cxv[j] - b * sxv[j]) * scale);
      e[28 + j] = f2bf((a * sxv[j] + b * cxv[j]) * scale);
      float a2 = bf2f(e[40 + j]), b2 = bf2f(e[52 + j]);
      e[40 + j] = f2bf((a2 * cyv[j] - b2 * syv[j]) * scale);
      e[52 + j] = f2bf((a2 * syv[j] + b2 * cyv[j]) * scale);
    }
#pragma unroll
    for (int v = 0; v < 8; ++v)
      *(short8v*)(p + 8 * v) = *(short8v*)&e[8 * v];
  } else {
    const int tb = bid - 2048;             // < 4096 = 16 st * 16 hd * 16 b
    const int t = threadIdx.x;
    const int st0 = (tb & 15) * 64;
    const int hd = (tb >> 4) & 15, b = tb >> 8;
    const unsigned short* src = vb + ((size_t)b * S_ + st0) * D_ + hd * 64;
#pragma unroll
    for (int rep = 0; rep < 4; ++rep) {
      int id = t + rep * 256;
      int s = id >> 4, n4 = (id & 15) * 4;
      short4v val = *(const short4v*)(src + (size_t)s * D_ + n4);
      T[n4 + 0][s] = val[0]; T[n4 + 1][s] = val[1];
      T[n4 + 2][s] = val[2]; T[n4 + 3][s] = val[3];
    }
    __syncthreads();
    unsigned short* dst = vT + ((size_t)(b * NH_ + hd) * 64) * S_ + st0;
#pragma unroll
    for (int rep = 0; rep < 2; ++rep) {
      int id = t + rep * 256;
      int n = id >> 3, s8 = (id & 7) * 8;
      unsigned short tmp[8];
#pragma unroll
      for (int u2 = 0; u2 < 8; ++u2) tmp[u2] = T[n][s8 + u2];
      *(short8v*)(dst + (size_t)n * S_ + s8) = *(short8v*)tmp;
    }
  }
}

// ---------------------------------------------------------------- MFMA flash attention
// grid = 2048 linear, swizzled: xcd=id%8, slot=id/8, qt=slot%8,
// pair=(slot/8)*8+xcd.  8 qt-blocks of a pair sit on ONE XCD -> K/V L2-resident.
// Block-shared double-buffered LDS K/V staging (round-4 2x win), swapped QK^T
// with in-register softmax, bpermute P-redistribution, truncation-consistent
// cvt_pk softmax (round-10, -14us).  Unchanged from round 10.
__global__ __launch_bounds__(256, 4) void attn_mfma(
    const unsigned short* __restrict__ qb, const unsigned short* __restrict__ kb,
    const unsigned short* __restrict__ vT, unsigned short* __restrict__ out) {
  __shared__ unsigned short KV[2][2][4096];   // [dbuf][K/V][64 rows x 64 elems]
  const int t = threadIdx.x;
  const int w = t >> 6;
  const int L = t & 63;
  const int c = L & 15;
  const int g = L >> 4;
  const int id = blockIdx.x;
  const int xcd = id & 7, slot = id >> 3;
  const int qt = slot & 7;
  const int pair = (slot >> 3) * 8 + xcd;
  const int b = pair >> 4, hd = pair & 15;
  const size_t mrow0 = (size_t)b * S_ + qt * 128 + w * 32;
  const int dcol0 = hd * 64;

  const int lrow = L >> 3;
  const int lcol = ((L & 7) ^ lrow) * 8;

  const int a_lo = (((L & 16) ? 32 : 0) + c) * 4;
  const int a_hi = a_lo + 64;
  const bool ghi = (L >= 32);
  const int swz = (c & 7) << 3;                   // read-side XOR (elems)

  short8v aq[2][2];
#pragma unroll
  for (int i = 0; i < 2; ++i)
#pragma unroll
    for (int st = 0; st < 2; ++st)
      aq[i][st] = *(const short8v*)(qb + (mrow0 + 16 * i + c) * D_ + dcol0 + 32 * st + 8 * g);

  float4v oacc[2][4];
  float lsum[2] = {0.f, 0.f};
#pragma unroll
  for (int i = 0; i < 2; ++i)
#pragma unroll
    for (int jv = 0; jv < 4; ++jv) oacc[i][jv] = (float4v){0.f, 0.f, 0.f, 0.f};

  const unsigned short* vbase = vT + (size_t)(b * NH_ + hd) * 64 * S_;
  const unsigned short* kbb = kb + (size_t)b * S_ * D_ + dcol0;

#define STAGE(buf, kt_)                                                          \
  {                                                                              \
    _Pragma("unroll")                                                            \
    for (int e = 0; e < 2; ++e) {                                                \
      const int seg = 2 * w + e;                                                 \
      const int row = seg * 8 + lrow;                                            \
      load_lds16(kbb + (size_t)((kt_) * 64 + row) * D_ + lcol,                   \
                 &KV[buf][0][seg * 512]);                                        \
      load_lds16(vbase + (size_t)row * S_ + (kt_) * 64 + lcol,                   \
                 &KV[buf][1][seg * 512]);                                        \
    }                                                                            \
  }

  STAGE(0, 0);
  asm volatile("s_waitcnt vmcnt(0)" ::: "memory");
  __syncthreads();

#pragma unroll 1
  for (int kt = 0; kt < 16; ++kt) {
    const int cur = kt & 1;
    if (kt < 15) STAGE(cur ^ 1, kt + 1);
#pragma unroll
    for (int st = 0; st < 2; ++st) {
      short8v vfh[4];
#pragma unroll
      for (int jv = 0; jv < 4; ++jv)
        vfh[jv] = *(const short8v*)&KV[cur][1][((16 * jv + c) * 64 + st * 32 + 8 * g) ^ swz];
      short8v kfh[2][2];
#pragma unroll
      for (int jl = 0; jl < 2; ++jl)
#pragma unroll
        for (int h = 0; h < 2; ++h)
          kfh[jl][h] = *(const short8v*)&KV[cur][0][((16 * (2 * st + jl) + c) * 64 + h * 32 + 8 * g) ^ swz];
      float4v sacch[2][2];
#pragma unroll
      for (int i = 0; i < 2; ++i)
#pragma unroll
        for (int jl = 0; jl < 2; ++jl) sacch[i][jl] = (float4v){0.f, 0.f, 0.f, 0.f};
      __builtin_amdgcn_s_setprio(1);
#pragma unroll
      for (int jl = 0; jl < 2; ++jl)
#pragma unroll
        for (int i = 0; i < 2; ++i) {
          sacch[i][jl] = __builtin_amdgcn_mfma_f32_16x16x32_bf16(kfh[jl][0], aq[i][0], sacch[i][jl], 0, 0, 0);
          sacch[i][jl] = __builtin_amdgcn_mfma_f32_16x16x32_bf16(kfh[jl][1], aq[i][1], sacch[i][jl], 0, 0, 0);
        }
      __builtin_amdgcn_s_setprio(0);
      // softmax: exp -> HW packed bf16 convert; denominator from the SAME
      // quantized values (truncation-consistent -> rounding bias cancels)
      unsigned pkh[2][2][2];
#pragma unroll
      for (int i = 0; i < 2; ++i)
#pragma unroll
        for (int jl = 0; jl < 2; ++jl) {
          float p0 = __expf(sacch[i][jl][0]);
          float p1 = __expf(sacch[i][jl][1]);
          float p2 = __expf(sacch[i][jl][2]);
          float p3 = __expf(sacch[i][jl][3]);
          const unsigned w0 = cvt_pk_bf16(p0, p1);
          const unsigned w1 = cvt_pk_bf16(p2, p3);
          pkh[i][jl][0] = w0;
          pkh[i][jl][1] = w1;
          union { unsigned u; float f; } t0, t1, t2, t3;
          t0.u = w0 << 16; t1.u = w0 & 0xffff0000u;
          t2.u = w1 << 16; t3.u = w1 & 0xffff0000u;
          lsum[i] += (t0.f + t1.f) + (t2.f + t3.f);
        }
      short8v aph[2];
#pragma unroll
      for (int i = 0; i < 2; ++i) {
        uint4v wv;
#pragma unroll
        for (int q2 = 0; q2 < 4; ++q2) {
          const int addr = (q2 & 2) ? a_hi : a_lo;
          int vlo = __builtin_amdgcn_ds_bpermute(addr, (int)pkh[i][0][q2 & 1]);
          int vhi = __builtin_amdgcn_ds_bpermute(addr, (int)pkh[i][1][q2 & 1]);
          wv[q2] = (unsigned)(ghi ? vhi : vlo);
        }
        aph[i] = *(short8v*)&wv;
      }
      __builtin_amdgcn_s_setprio(1);
#pragma unroll
      for (int jv = 0; jv < 4; ++jv)
#pragma unroll
        for (int i = 0; i < 2; ++i)
          oacc[i][jv] = __builtin_amdgcn_mfma_f32_16x16x32_bf16(aph[i], vfh[jv], oacc[i][jv], 0, 0, 0);
      __builtin_amdgcn_s_setprio(0);
    }
    asm volatile("s_waitcnt vmcnt(0)" ::: "memory");
    __syncthreads();
  }
#undef STAGE
#pragma unroll
  for (int i = 0; i < 2; ++i) {
    float ls = lsum[i];
    ls += __shfl_xor(ls, 16);
    ls += __shfl_xor(ls, 32);
#pragma unroll
    for (int r = 0; r < 4; ++r) {
      float inv = 1.f / __shfl(ls, 4 * g + r);
      size_t row = mrow0 + 16 * i + 4 * g + r;
#pragma unroll
      for (int jv = 0; jv < 4; ++jv)
        out[row * D_ + dcol0 + 16 * jv + c] = f2bf(oacc[i][jv][r] * inv);
    }
  }
}

// ---------------------------------------------------------------- launch
// Workspace (peak 168.03 MB < 192 MB proven):
//   [0,32)MB xb (reused as ob after QKV gemms) | [32,64) qb | [64,96) kb
//   [96,128) vb | [128,160) vT | [160,168) wqb..wob | [168,+32KB) tables
extern "C" void kernel_launch(void* const* d_in, const int* in_sizes, int n_in,
                              void* d_out, int out_size, void* d_ws, size_t ws_size,
                              hipStream_t stream) {
  const float* x  = (const float*)d_in[0];
  const float* Wq = (const float*)d_in[1];
  const float* bq = (const float*)d_in[2];
  const float* Wk = (const float*)d_in[3];
  const float* bk = (const float*)d_in[4];
  const float* Wv = (const float*)d_in[5];
  const float* bv = (const float*)d_in[6];
  const float* Wo = (const float*)d_in[7];
  const float* bo = (const float*)d_in[8];
  float* out = (float*)d_out;

  char* ws = (char*)d_ws;
  const size_t SZ2 = (size_t)M_TOT * D_ * 2;   // 32 MB
  unsigned short* xb = (unsigned short*)(ws);
  unsigned short* ob = xb;                               // alias: free after QKV gemms
  unsigned short* qb = (unsigned short*)(ws + SZ2);
  unsigned short* kb = (unsigned short*)(ws + 2 * SZ2);
  unsigned short* vb = (unsigned short*)(ws + 3 * SZ2);
  unsigned short* vT = (unsigned short*)(ws + 4 * SZ2);
  unsigned short* wqb = (unsigned short*)(ws + 5 * SZ2);
  unsigned short* wob = wqb + 3 * (size_t)D_ * D_;
  float* cos1 = (float*)(ws + 5 * SZ2 + 4 * (size_t)D_ * D_ * 2);
  float* sin1 = cos1 + S_ * 8;
  float* cos2 = sin1 + S_ * 8;
  float* sin2 = cos2 + 384;

  // 1) tables + x->bf16 + 4 weights->bf16
  prep<<<20514, 256, 0, stream>>>(x, xb, Wq, Wk, Wv, Wo, wqb,
                                  cos1, sin1, cos2, sin2);
  // 2) Q,K,V projections in one launch (grid.y selects W/bias/output)
  gemm_mfma<true><<<dim3(512, 3), 512, 0, stream>>>(xb, wqb, bq, bk, bv, qb);
  // 3) ropeQ + ropeK + V-transpose in one launch
  postproc<<<6144, 256, 0, stream>>>(qb, kb, vb, vT, cos1, sin1, cos2, sin2);
  // 4) attention
  attn_mfma<<<2048, 256, 0, stream>>>(qb, kb, vT, ob);
  // 5) output projection (f32 out)
  gemm_mfma<false><<<dim3(512, 1), 512, 0, stream>>>(ob, wob, bo, bo, bo, out);
}

// Round 12
// 416.878 us; speedup vs baseline: 1.1776x; 1.0231x over previous
//
#include <hip/hip_runtime.h>
#include <math.h>

#define B_ 16
#define S_ 1024
#define D_ 1024
#define NH_ 16
#define M_TOT (B_ * S_)

typedef __attribute__((ext_vector_type(8))) short short8v;
typedef __attribute__((ext_vector_type(4))) short short4v;
typedef __attribute__((ext_vector_type(4))) float float4v;
typedef __attribute__((ext_vector_type(4))) unsigned int uint4v;

static __device__ __forceinline__ unsigned short f2bf(float f) {
  union { float f; unsigned u; } x; x.f = f;
  unsigned r = (x.u + 0x7fffu + ((x.u >> 16) & 1u)) >> 16;
  return (unsigned short)r;
}
static __device__ __forceinline__ float bf2f(unsigned short u) {
  union { unsigned u; float f; } x; x.u = ((unsigned)u) << 16;
  return x.f;
}

// HW packed convert f32x2 -> bf16x2 (src0 -> LOW half).  Rounding differs from
// RNE; SAFE only when numerator and denominator share the quantization
// (round-10 proven: truncation-consistent softmax, bias cancels).
static __device__ __forceinline__ unsigned cvt_pk_bf16(float a, float b) {
  unsigned r;
  asm("v_cvt_pk_bf16_f32 %0, %1, %2" : "=v"(r) : "v"(a), "v"(b));
  return r;
}

// async global->LDS, 16B per lane; LDS dest = wave-uniform base + lane*16 (m104)
static __device__ __forceinline__ void load_lds16(const unsigned short* g, unsigned short* l) {
  __builtin_amdgcn_global_load_lds(
      (const __attribute__((address_space(1))) unsigned int*)g,
      (__attribute__((address_space(3))) unsigned int*)l, 16, 0, 0);
}

// ---------------------------------------------------------------- fused prep
// [0, 16384)        : x f32 -> bf16 (4 elems/thread)
// [16384, 20480)    : 4 weight matrices f32 -> bf16 (4 elems/thread)
// [20480, 20514)    : RoPE tables
__global__ __launch_bounds__(256) void prep(
    const float* __restrict__ x, unsigned short* __restrict__ xb,
    const float* __restrict__ w0, const float* __restrict__ w1,
    const float* __restrict__ w2, const float* __restrict__ w3,
    unsigned short* __restrict__ wdst,
    float* __restrict__ cos1, float* __restrict__ sin1,
    float* __restrict__ cos2, float* __restrict__ sin2) {
  const int bid = blockIdx.x;
  if (bid < 16384) {
    int i = bid * 256 + threadIdx.x;       // < M_TOT*D_/4
    float4 v = ((const float4*)x)[i];
    unsigned short tt[4] = {f2bf(v.x), f2bf(v.y), f2bf(v.z), f2bf(v.w)};
    ((short4v*)xb)[i] = *(short4v*)tt;
  } else if (bid < 20480) {
    int wi = (bid - 16384) * 256 + threadIdx.x;   // < 4*D_*D_/4
    int m = wi >> 18;                             // matrix (block-uniform)
    int i = wi & 262143;
    const float* src = (m == 0) ? w0 : (m == 1) ? w1 : (m == 2) ? w2 : w3;
    float4 v = ((const float4*)src)[i];
    unsigned short tt[4] = {f2bf(v.x), f2bf(v.y), f2bf(v.z), f2bf(v.w)};
    ((short4v*)(wdst + (size_t)m * D_ * D_))[i] = *(short4v*)tt;
  } else {
    int t = (bid - 20480) * 256 + threadIdx.x;
    if (t < S_ * 8) {
      int s = t >> 3, i = t & 7;
      double ang = (double)s * pow(10000.0, -(double)i / 8.0);
      cos1[t] = (float)cos(ang);
      sin1[t] = (float)sin(ang);
    } else if (t < S_ * 8 + 384) {
      int u = t - S_ * 8;
      int p = u / 12, j = u - p * 12;
      double ang = (double)p * pow(10000.0, -(double)j / 12.0);
      cos2[u] = (float)cos(ang);
      sin2[u] = (float)sin(ang);
    }
  }
}

// ---------------------------------------------------------------- bf16 MFMA GEMM
// C[M,1024] = A[M,1024] @ W[1024,1024]^T + bias.
// 128x256 tile, 512 threads = 8 waves (2M x 4N), per-wave 64x64 out, BK=32.
// Sync skeleton: round-7 T4 counted vmcnt, 3 LDS buffers, raw s_barrier.
//
// Round-12: 2-row/32B-granule LDS swizzle.  Diagnosis: per-step wall 2940cy ==
// LDS-peak 1024cy x 2.8 (the 8-way-conflict multiplier, m136) -> GEMM is now
// LDS-read-bound with conflicts as the multiplier (regime changed vs round 8:
// staging no longer critical).  Swizzle: data for global byte Y sits at LDS
// byte X = Y ^ (((Y>>7)&3)<<5) -- XOR of byte bits 5,6 with 2 row bits inside
// each 128B (2-row) block.  Banks spread 8-way -> 4-way (2.94x -> 1.58x).
// Granule = 32B: every lane-quad's global source order stays in ascending 32B
// runs (round-8's 16B-granule perm had descending 16B orders -> suspected DMA
// lane-merge break -> regression; this avoids it).
//   stage (LDS dest linear, rule #21): srcrow = (t>>2) ^ ((t>>4)&1),
//                                      srcchunk16 = (t&3) ^ (((t>>3)&1)<<1)
//   read: elem_idx = (row*32 + 8g) ^ (((c>>1)&3)<<4)   (key per-lane const)
// Involution verified: LDS(row2,chk2)<-global(2,chk0)<-lane10; in-bounds since
// XOR stays within 128B-aligned row pairs.
// grid.y selects {W, bias, C} (QKV fused in one launch; O uses y=0).
template <bool BF16OUT>
__global__ __launch_bounds__(512, 4) void gemm_mfma(
    const unsigned short* __restrict__ A, const unsigned short* __restrict__ Wall,
    const float* __restrict__ b0, const float* __restrict__ b1,
    const float* __restrict__ b2, void* __restrict__ Cout) {
  __shared__ unsigned short As[3][128 * 32];   // 8 KB / buf
  __shared__ unsigned short Bs[3][256 * 32];   // 16 KB / buf
  const int y = blockIdx.y;
  const unsigned short* W = Wall + (size_t)y * D_ * D_;
  const float* bias = (y == 0) ? b0 : (y == 1) ? b1 : b2;
  const int t = threadIdx.x;            // 0..511
  const int wid = t >> 6, L = t & 63;
  const int c = L & 15, g = L >> 4;
  const int id = blockIdx.x;            // 0..511
  const int xcd = id & 7, slot = id >> 3;
  const int bn = (slot & 3) * 256;      // 4 n-blocks
  const int bm = ((slot >> 2) * 8 + xcd) * 128;   // 128 m-blocks

  // staging with inverse swizzle on the GLOBAL side (LDS dest stays linear):
  const int srow = (t >> 2) ^ ((t >> 4) & 1);          // row bit0 ^= key>>1
  const int sko = ((t & 3) ^ (((t >> 3) & 1) << 1)) * 8;  // chunk bit1 ^= key&1
  const unsigned short* gA = A + (size_t)(bm + srow) * D_ + sko;
  const unsigned short* gB = W + (size_t)(bn + srow) * D_ + sko;

  const int wm = (wid >> 2) * 64, wn = (wid & 3) * 64;
  const int rkey = ((c >> 1) & 3) << 4;                // read-side elem XOR

  float4v acc[4][4];
#pragma unroll
  for (int i = 0; i < 4; ++i)
#pragma unroll
    for (int j = 0; j < 4; ++j) acc[i][j] = (float4v){0.f, 0.f, 0.f, 0.f};

#define GS(buf, kt_)                                                     \
  {                                                                      \
    load_lds16(gA + (kt_) * 32, &As[buf][wid * 512]);                    \
    load_lds16(gB + (kt_) * 32, &Bs[buf][wid * 512]);                    \
    load_lds16(gB + (kt_) * 32 + 128 * D_, &Bs[buf][wid * 512 + 4096]);  \
  }
#define VWAIT3 asm volatile("s_waitcnt vmcnt(3)" ::: "memory")
#define VWAIT0 asm volatile("s_waitcnt vmcnt(0)" ::: "memory")
#define BARRIER asm volatile("s_barrier" ::: "memory")
#define COMPUTE(cur)                                                           \
  {                                                                            \
    short8v af[4], bf[4];                                                      \
    _Pragma("unroll")                                                          \
    for (int i = 0; i < 4; ++i)                                                \
      af[i] = *(const short8v*)&As[cur][((wm + 16 * i + c) * 32 + 8 * g) ^ rkey]; \
    _Pragma("unroll")                                                          \
    for (int j = 0; j < 4; ++j)                                                \
      bf[j] = *(const short8v*)&Bs[cur][((wn + 16 * j + c) * 32 + 8 * g) ^ rkey]; \
    _Pragma("unroll")                                                          \
    for (int i = 0; i < 4; ++i)                                                \
      _Pragma("unroll")                                                        \
      for (int j = 0; j < 4; ++j)                                              \
        acc[i][j] = __builtin_amdgcn_mfma_f32_16x16x32_bf16(                   \
            af[i], bf[j], acc[i][j], 0, 0, 0);                                 \
  }

  GS(0, 0);          // outstanding 3
  GS(1, 1);          // outstanding 6
#pragma unroll 1
  for (int s = 0; s < 30; s += 3) {
    VWAIT3; BARRIER; GS(2, s + 2); COMPUTE(0);   // step s
    VWAIT3; BARRIER; GS(0, s + 3); COMPUTE(1);   // step s+1
    VWAIT3; BARRIER; GS(1, s + 4); COMPUTE(2);   // step s+2
  }
  VWAIT3; BARRIER; COMPUTE(0);                   // step 30 (k30 in buf0)
  VWAIT0; BARRIER; COMPUTE(1);                   // step 31 (k31 in buf1)
#undef GS
#undef VWAIT3
#undef VWAIT0
#undef BARRIER
#undef COMPUTE
  unsigned short* Cb = (unsigned short*)Cout + (size_t)y * M_TOT * D_;
#pragma unroll
  for (int i = 0; i < 4; ++i)
#pragma unroll
    for (int r = 0; r < 4; ++r) {
      const size_t row = (size_t)bm + wm + 16 * i + 4 * g + r;
#pragma unroll
      for (int j = 0; j < 4; ++j) {
        const int col = bn + wn + 16 * j + c;
        float vv = acc[i][j][r] + bias[col];
        if (BF16OUT)
          Cb[row * D_ + col] = f2bf(vv);
        else
          ((float*)Cout)[row * D_ + col] = vv;
      }
    }
}

// ---------------------------------------------------------------- fused postproc
// [0, 1024)       : RoPE on Q, vectorized: 1 thread per (token, head) owns the
//                   full 64-elem head (128B); all rotation pairs thread-internal.
//                   scale 0.125 (EXACT in bf16; log2e-fold banned: 0.125*log2e
//                   not bf16-representable -> round-5 accuracy failure)
// [1024, 2048)    : RoPE on K (scale 1.0), same structure
// [2048, 6144)    : V transpose vb [b][s][hd*64+n] -> vT [b][hd][n][s]
__global__ __launch_bounds__(256) void postproc(
    unsigned short* __restrict__ qb, unsigned short* __restrict__ kbuf,
    const unsigned short* __restrict__ vb, unsigned short* __restrict__ vT,
    const float* __restrict__ cos1, const float* __restrict__ sin1,
    const float* __restrict__ cos2, const float* __restrict__ sin2) {
  __shared__ unsigned short T[64][72];
  const int bid = blockIdx.x;
  if (bid < 2048) {
    const int qk = bid >> 10;                       // 0 = Q, 1 = K
    unsigned short* buf = qk ? kbuf : qb;
    const float scale = qk ? 1.0f : 0.125f;
    const int tid = ((bid & 1023) << 8) + threadIdx.x;   // < 262144
    const int m = tid >> 4, head = tid & 15;
    const int s = m & (S_ - 1);
    const int xx = s & 31, yy = s >> 5;
    unsigned short* p = buf + (size_t)m * D_ + head * 64;

    unsigned short e[64];
#pragma unroll
    for (int v = 0; v < 8; ++v)
      *(short8v*)&e[8 * v] = *(const short8v*)(p + 8 * v);

    float c1v[8], s1v[8], cxv[12], sxv[12], cyv[12], syv[12];
#pragma unroll
    for (int i = 0; i < 8; ++i) {
      c1v[i] = cos1[s * 8 + i]; s1v[i] = sin1[s * 8 + i];
    }
#pragma unroll
    for (int j = 0; j < 12; ++j) {
      cxv[j] = cos2[xx * 12 + j]; sxv[j] = sin2[xx * 12 + j];
      cyv[j] = cos2[yy * 12 + j]; syv[j] = sin2[yy * 12 + j];
    }
#pragma unroll
    for (int i = 0; i < 8; ++i) {
      float a = bf2f(e[2 * i]), b = bf2f(e[2 * i + 1]);
      e[2 * i]     = f2bf((a * c1v[i] - b * s1v[i]) * scale);
      e[2 * i + 1] = f2bf((a * s1v[i] + b * c1v[i]) * scale);
    }
#pragma unroll
    for (int j = 0; j < 12; ++j) {
      float a = bf2f(e[16 + j]), b = bf2f(e[28 + j]);
      e[16 + j] = f2bf((a * cxv[j] - b * sxv[j]) * scale);
      e[28 + j] = f2bf((a * sxv[j] + b * cxv[j]) * scale);
      float a2 = bf2f(e[40 + j]), b2 = bf2f(e[52 + j]);
      e[40 + j] = f2bf((a2 * cyv[j] - b2 * syv[j]) * scale);
      e[52 + j] = f2bf((a2 * syv[j] + b2 * cyv[j]) * scale);
    }
#pragma unroll
    for (int v = 0; v < 8; ++v)
      *(short8v*)(p + 8 * v) = *(short8v*)&e[8 * v];
  } else {
    const int tb = bid - 2048;             // < 4096 = 16 st * 16 hd * 16 b
    const int t = threadIdx.x;
    const int st0 = (tb & 15) * 64;
    const int hd = (tb >> 4) & 15, b = tb >> 8;
    const unsigned short* src = vb + ((size_t)b * S_ + st0) * D_ + hd * 64;
#pragma unroll
    for (int rep = 0; rep < 4; ++rep) {
      int id = t + rep * 256;
      int s = id >> 4, n4 = (id & 15) * 4;
      short4v val = *(const short4v*)(src + (size_t)s * D_ + n4);
      T[n4 + 0][s] = val[0]; T[n4 + 1][s] = val[1];
      T[n4 + 2][s] = val[2]; T[n4 + 3][s] = val[3];
    }
    __syncthreads();
    unsigned short* dst = vT + ((size_t)(b * NH_ + hd) * 64) * S_ + st0;
#pragma unroll
    for (int rep = 0; rep < 2; ++rep) {
      int id = t + rep * 256;
      int n = id >> 3, s8 = (id & 7) * 8;
      unsigned short tmp[8];
#pragma unroll
      for (int u2 = 0; u2 < 8; ++u2) tmp[u2] = T[n][s8 + u2];
      *(short8v*)(dst + (size_t)n * S_ + s8) = *(short8v*)tmp;
    }
  }
}

// ---------------------------------------------------------------- MFMA flash attention
// grid = 2048 linear, swizzled: xcd=id%8, slot=id/8, qt=slot%8,
// pair=(slot/8)*8+xcd.  8 qt-blocks of a pair sit on ONE XCD -> K/V L2-resident.
// Block-shared double-buffered LDS K/V staging (round-4 2x win), swapped QK^T
// with in-register softmax, bpermute P-redistribution, truncation-consistent
// cvt_pk softmax (round-10, -14us).  Unchanged from round 10.
__global__ __launch_bounds__(256, 4) void attn_mfma(
    const unsigned short* __restrict__ qb, const unsigned short* __restrict__ kb,
    const unsigned short* __restrict__ vT, unsigned short* __restrict__ out) {
  __shared__ unsigned short KV[2][2][4096];   // [dbuf][K/V][64 rows x 64 elems]
  const int t = threadIdx.x;
  const int w = t >> 6;
  const int L = t & 63;
  const int c = L & 15;
  const int g = L >> 4;
  const int id = blockIdx.x;
  const int xcd = id & 7, slot = id >> 3;
  const int qt = slot & 7;
  const int pair = (slot >> 3) * 8 + xcd;
  const int b = pair >> 4, hd = pair & 15;
  const size_t mrow0 = (size_t)b * S_ + qt * 128 + w * 32;
  const int dcol0 = hd * 64;

  const int lrow = L >> 3;
  const int lcol = ((L & 7) ^ lrow) * 8;

  const int a_lo = (((L & 16) ? 32 : 0) + c) * 4;
  const int a_hi = a_lo + 64;
  const bool ghi = (L >= 32);
  const int swz = (c & 7) << 3;                   // read-side XOR (elems)

  short8v aq[2][2];
#pragma unroll
  for (int i = 0; i < 2; ++i)
#pragma unroll
    for (int st = 0; st < 2; ++st)
      aq[i][st] = *(const short8v*)(qb + (mrow0 + 16 * i + c) * D_ + dcol0 + 32 * st + 8 * g);

  float4v oacc[2][4];
  float lsum[2] = {0.f, 0.f};
#pragma unroll
  for (int i = 0; i < 2; ++i)
#pragma unroll
    for (int jv = 0; jv < 4; ++jv) oacc[i][jv] = (float4v){0.f, 0.f, 0.f, 0.f};

  const unsigned short* vbase = vT + (size_t)(b * NH_ + hd) * 64 * S_;
  const unsigned short* kbb = kb + (size_t)b * S_ * D_ + dcol0;

#define STAGE(buf, kt_)                                                          \
  {                                                                              \
    _Pragma("unroll")                                                            \
    for (int e = 0; e < 2; ++e) {                                                \
      const int seg = 2 * w + e;                                                 \
      const int row = seg * 8 + lrow;                                            \
      load_lds16(kbb + (size_t)((kt_) * 64 + row) * D_ + lcol,                   \
                 &KV[buf][0][seg * 512]);                                        \
      load_lds16(vbase + (size_t)row * S_ + (kt_) * 64 + lcol,                   \
                 &KV[buf][1][seg * 512]);                                        \
    }                                                                            \
  }

  STAGE(0, 0);
  asm volatile("s_waitcnt vmcnt(0)" ::: "memory");
  __syncthreads();

#pragma unroll 1
  for (int kt = 0; kt < 16; ++kt) {
    const int cur = kt & 1;
    if (kt < 15) STAGE(cur ^ 1, kt + 1);
#pragma unroll
    for (int st = 0; st < 2; ++st) {
      short8v vfh[4];
#pragma unroll
      for (int jv = 0; jv < 4; ++jv)
        vfh[jv] = *(const short8v*)&KV[cur][1][((16 * jv + c) * 64 + st * 32 + 8 * g) ^ swz];
      short8v kfh[2][2];
#pragma unroll
      for (int jl = 0; jl < 2; ++jl)
#pragma unroll
        for (int h = 0; h < 2; ++h)
          kfh[jl][h] = *(const short8v*)&KV[cur][0][((16 * (2 * st + jl) + c) * 64 + h * 32 + 8 * g) ^ swz];
      float4v sacch[2][2];
#pragma unroll
      for (int i = 0; i < 2; ++i)
#pragma unroll
        for (int jl = 0; jl < 2; ++jl) sacch[i][jl] = (float4v){0.f, 0.f, 0.f, 0.f};
      __builtin_amdgcn_s_setprio(1);
#pragma unroll
      for (int jl = 0; jl < 2; ++jl)
#pragma unroll
        for (int i = 0; i < 2; ++i) {
          sacch[i][jl] = __builtin_amdgcn_mfma_f32_16x16x32_bf16(kfh[jl][0], aq[i][0], sacch[i][jl], 0, 0, 0);
          sacch[i][jl] = __builtin_amdgcn_mfma_f32_16x16x32_bf16(kfh[jl][1], aq[i][1], sacch[i][jl], 0, 0, 0);
        }
      __builtin_amdgcn_s_setprio(0);
      // softmax: exp -> HW packed bf16 convert; denominator from the SAME
      // quantized values (truncation-consistent -> rounding bias cancels)
      unsigned pkh[2][2][2];
#pragma unroll
      for (int i = 0; i < 2; ++i)
#pragma unroll
        for (int jl = 0; jl < 2; ++jl) {
          float p0 = __expf(sacch[i][jl][0]);
          float p1 = __expf(sacch[i][jl][1]);
          float p2 = __expf(sacch[i][jl][2]);
          float p3 = __expf(sacch[i][jl][3]);
          const unsigned w0 = cvt_pk_bf16(p0, p1);
          const unsigned w1 = cvt_pk_bf16(p2, p3);
          pkh[i][jl][0] = w0;
          pkh[i][jl][1] = w1;
          union { unsigned u; float f; } t0, t1, t2, t3;
          t0.u = w0 << 16; t1.u = w0 & 0xffff0000u;
          t2.u = w1 << 16; t3.u = w1 & 0xffff0000u;
          lsum[i] += (t0.f + t1.f) + (t2.f + t3.f);
        }
      short8v aph[2];
#pragma unroll
      for (int i = 0; i < 2; ++i) {
        uint4v wv;
#pragma unroll
        for (int q2 = 0; q2 < 4; ++q2) {
          const int addr = (q2 & 2) ? a_hi : a_lo;
          int vlo = __builtin_amdgcn_ds_bpermute(addr, (int)pkh[i][0][q2 & 1]);
          int vhi = __builtin_amdgcn_ds_bpermute(addr, (int)pkh[i][1][q2 & 1]);
          wv[q2] = (unsigned)(ghi ? vhi : vlo);
        }
        aph[i] = *(short8v*)&wv;
      }
      __builtin_amdgcn_s_setprio(1);
#pragma unroll
      for (int jv = 0; jv < 4; ++jv)
#pragma unroll
        for (int i = 0; i < 2; ++i)
          oacc[i][jv] = __builtin_amdgcn_mfma_f32_16x16x32_bf16(aph[i], vfh[jv], oacc[i][jv], 0, 0, 0);
      __builtin_amdgcn_s_setprio(0);
    }
    asm volatile("s_waitcnt vmcnt(0)" ::: "memory");
    __syncthreads();
  }
#undef STAGE
#pragma unroll
  for (int i = 0; i < 2; ++i) {
    float ls = lsum[i];
    ls += __shfl_xor(ls, 16);
    ls += __shfl_xor(ls, 32);
#pragma unroll
    for (int r = 0; r < 4; ++r) {
      float inv = 1.f / __shfl(ls, 4 * g + r);
      size_t row = mrow0 + 16 * i + 4 * g + r;
#pragma unroll
      for (int jv = 0; jv < 4; ++jv)
        out[row * D_ + dcol0 + 16 * jv + c] = f2bf(oacc[i][jv][r] * inv);
    }
  }
}

// ---------------------------------------------------------------- launch
// Workspace (peak 168.03 MB < 192 MB proven):
//   [0,32)MB xb (reused as ob after QKV gemms) | [32,64) qb | [64,96) kb
//   [96,128) vb | [128,160) vT | [160,168) wqb..wob | [168,+32KB) tables
extern "C" void kernel_launch(void* const* d_in, const int* in_sizes, int n_in,
                              void* d_out, int out_size, void* d_ws, size_t ws_size,
                              hipStream_t stream) {
  const float* x  = (const float*)d_in[0];
  const float* Wq = (const float*)d_in[1];
  const float* bq = (const float*)d_in[2];
  const float* Wk = (const float*)d_in[3];
  const float* bk = (const float*)d_in[4];
  const float* Wv = (const float*)d_in[5];
  const float* bv = (const float*)d_in[6];
  const float* Wo = (const float*)d_in[7];
  const float* bo = (const float*)d_in[8];
  float* out = (float*)d_out;

  char* ws = (char*)d_ws;
  const size_t SZ2 = (size_t)M_TOT * D_ * 2;   // 32 MB
  unsigned short* xb = (unsigned short*)(ws);
  unsigned short* ob = xb;                               // alias: free after QKV gemms
  unsigned short* qb = (unsigned short*)(ws + SZ2);
  unsigned short* kb = (unsigned short*)(ws + 2 * SZ2);
  unsigned short* vb = (unsigned short*)(ws + 3 * SZ2);
  unsigned short* vT = (unsigned short*)(ws + 4 * SZ2);
  unsigned short* wqb = (unsigned short*)(ws + 5 * SZ2);
  unsigned short* wob = wqb + 3 * (size_t)D_ * D_;
  float* cos1 = (float*)(ws + 5 * SZ2 + 4 * (size_t)D_ * D_ * 2);
  float* sin1 = cos1 + S_ * 8;
  float* cos2 = sin1 + S_ * 8;
  float* sin2 = cos2 + 384;

  // 1) tables + x->bf16 + 4 weights->bf16
  prep<<<20514, 256, 0, stream>>>(x, xb, Wq, Wk, Wv, Wo, wqb,
                                  cos1, sin1, cos2, sin2);
  // 2) Q,K,V projections in one launch (grid.y selects W/bias/output)
  gemm_mfma<true><<<dim3(512, 3), 512, 0, stream>>>(xb, wqb, bq, bk, bv, qb);
  // 3) ropeQ + ropeK + V-transpose in one launch
  postproc<<<6144, 256, 0, stream>>>(qb, kb, vb, vT, cos1, sin1, cos2, sin2);
  // 4) attention
  attn_mfma<<<2048, 256, 0, stream>>>(qb, kb, vT, ob);
  // 5) output projection (f32 out)
  gemm_mfma<false><<<dim3(512, 1), 512, 0, stream>>>(ob, wob, bo, bo, bo, out);
}